// Round 6
// baseline (369.278 us; speedup 1.0000x reference)
//
#include <hip/hip_runtime.h>
#include <hip/hip_bf16.h>

// DGCNN forward: 3×GCNConv(+score convs) -> SortPool(k=30) -> Conv1d stack -> MLP
// Round 5: fuse gemm64 into gfin1 epilogue; drop scan2; merge sortpool+cnn.
#define NN 50000
#define EE 600000
#define FIN 128
#define GG 500
#define NPG 100
#define KK 30
#define SCHUNK 1024

// ---------------- graph prep ----------------
__global__ void psg_deg(const int* __restrict__ dst, int* __restrict__ deg, int e) {
    int i = blockIdx.x * blockDim.x + threadIdx.x;
    if (i < e) atomicAdd(&deg[dst[i]], 1);
}

// exclusive scan of deg -> rowptr (chunked, raw chunk totals in csums); dinv = (deg+1)^-1/2
__global__ __launch_bounds__(SCHUNK) void psg_scan1(const int* __restrict__ deg,
                                                    int* __restrict__ rowptr,
                                                    int* __restrict__ csums,
                                                    float* __restrict__ dinv, int n) {
    __shared__ int sm[SCHUNK];
    int t = threadIdx.x;
    int base = blockIdx.x * SCHUNK;
    int v = (base + t < n) ? deg[base + t] : 0;
    sm[t] = v;
    __syncthreads();
    for (int off = 1; off < SCHUNK; off <<= 1) {
        int u = (t >= off) ? sm[t - off] : 0;
        __syncthreads();
        sm[t] += u;
        __syncthreads();
    }
    if (base + t < n) {
        rowptr[base + t] = sm[t] - v;  // exclusive within chunk
        dinv[base + t] = 1.0f / sqrtf((float)(v + 1));
    }
    if (t == SCHUNK - 1) csums[blockIdx.x] = sm[t];
}

// add prefix of csums (computed in-block; nchunk<=64) ; init rowfill; rowptr[n]=e
__global__ __launch_bounds__(SCHUNK) void psg_scan3(int* __restrict__ rowptr,
                                                    int* __restrict__ rowfill,
                                                    const int* __restrict__ csums,
                                                    int n, int e) {
    __shared__ int soff;
    int t = threadIdx.x;
    if (t < 64) {
        int c = (t < (int)blockIdx.x) ? csums[t] : 0;  // blockIdx.x <= 48 < 64
#pragma unroll
        for (int o = 1; o < 64; o <<= 1) c += __shfl_xor(c, o, 64);
        if (t == 0) soff = c;
    }
    __syncthreads();
    int i = blockIdx.x * SCHUNK + t;
    if (i < n) {
        int v = rowptr[i] + soff;
        rowptr[i] = v;
        rowfill[i] = v;
    }
    if (i == 0) rowptr[n] = e;
}

// bucket edges by dst: csr_src[pos] = src
__global__ void psg_build(const int* __restrict__ src, const int* __restrict__ dst,
                          int* __restrict__ rowfill, int* __restrict__ csr_src, int e) {
    int i = blockIdx.x * blockDim.x + threadIdx.x;
    if (i < e) {
        int pos = atomicAdd(&rowfill[dst[i]], 1);
        csr_src[pos] = src[i];
    }
}

// ---------------- GEMM: hs = (X @ W) * dinv ----------------
template <int KD>
__global__ __launch_bounds__(256) void psg_gemm(const float* __restrict__ X,
                                                const float* __restrict__ W,
                                                const float* __restrict__ dinv,
                                                float* __restrict__ hs, int n) {
    __shared__ __align__(16) float Xl[16][KD];
    __shared__ __align__(16) float WtF[(KD / 4) * 64 * 4];
    int t = threadIdx.x;
    int r0 = blockIdx.x * 16;
    for (int i = t; i < KD * 64; i += 256) {
        int k = i >> 6, j = i & 63;
        WtF[(((k >> 2) * 64 + j) << 2) + (k & 3)] = W[i];
    }
    for (int i4 = t; i4 < 16 * (KD / 4); i4 += 256) {
        int r = i4 / (KD / 4), u = i4 % (KD / 4);
        int row = r0 + r;
        float4 v = make_float4(0.f, 0.f, 0.f, 0.f);
        if (row < n) v = ((const float4*)(X + (size_t)row * KD))[u];
        ((float4*)&Xl[r][0])[u] = v;
    }
    __syncthreads();
    int j = t & 63, q = t >> 6;
    const float4* Wt4 = (const float4*)WtF;
    float a0 = 0.f, a1 = 0.f, a2 = 0.f, a3 = 0.f;
#pragma unroll 4
    for (int u = 0; u < KD / 4; ++u) {
        float4 wv = Wt4[u * 64 + j];
        float4 x0 = *(const float4*)&Xl[q * 4 + 0][u * 4];
        float4 x1 = *(const float4*)&Xl[q * 4 + 1][u * 4];
        float4 x2 = *(const float4*)&Xl[q * 4 + 2][u * 4];
        float4 x3 = *(const float4*)&Xl[q * 4 + 3][u * 4];
        a0 += x0.x * wv.x + x0.y * wv.y + x0.z * wv.z + x0.w * wv.w;
        a1 += x1.x * wv.x + x1.y * wv.y + x1.z * wv.z + x1.w * wv.w;
        a2 += x2.x * wv.x + x2.y * wv.y + x2.z * wv.z + x2.w * wv.w;
        a3 += x3.x * wv.x + x3.y * wv.y + x3.z * wv.z + x3.w * wv.w;
    }
    float av[4] = {a0, a1, a2, a3};
#pragma unroll
    for (int rr = 0; rr < 4; rr++) {
        int row = r0 + q * 4 + rr;
        if (row < n) hs[(size_t)row * 64 + j] = av[rr] * dinv[row];
    }
}

// ---------------- gather + finish (+ optional fused next-layer GEMM): one wave per node, ILP-8 ----
// acc = hs[node] + sum_{nbr} hs[nbr]; h = relu(acc*dinv + b); fused 64->1 dots;
// if FUSE: hs_next = (h_row @ Wn) * dinv   (next conv's message values)
template <int NDOT, bool FUSE>
__global__ __launch_bounds__(256) void psg_gfin(const float* __restrict__ hs,
                                                const int* __restrict__ rowptr,
                                                const int* __restrict__ csr_src,
                                                const float* __restrict__ dinv,
                                                const float* __restrict__ b,
                                                float* __restrict__ h,
                                                const float* __restrict__ wv0,
                                                float* __restrict__ s0_src,
                                                const float* __restrict__ wv1,
                                                float* __restrict__ s1_src,
                                                const float* __restrict__ Wn,
                                                float* __restrict__ hs_next, int n) {
    __shared__ float Wnl[64 * 64];  // only used when FUSE
    int t = threadIdx.x;
    if (FUSE) {
        for (int i = t; i < 64 * 64; i += 256) Wnl[i] = Wn[i];
    }
    int w = (int)((blockIdx.x * 256 + t) >> 6);
    int j = t & 63;
    bool valid = (w < n);
    float v = 0.f, di = 0.f;
    if (valid) {
        int p0 = rowptr[w], p1 = rowptr[w + 1];
        float a0 = hs[(size_t)w * 64 + j];  // self loop
        float a1 = 0.f, a2 = 0.f, a3 = 0.f, a4 = 0.f, a5 = 0.f, a6 = 0.f, a7 = 0.f;
        int p = p0;
        for (; p + 8 <= p1; p += 8) {
            int s0 = csr_src[p],     s1 = csr_src[p + 1], s2 = csr_src[p + 2], s3 = csr_src[p + 3];
            int s4 = csr_src[p + 4], s5 = csr_src[p + 5], s6 = csr_src[p + 6], s7 = csr_src[p + 7];
            a0 += hs[(size_t)s0 * 64 + j];
            a1 += hs[(size_t)s1 * 64 + j];
            a2 += hs[(size_t)s2 * 64 + j];
            a3 += hs[(size_t)s3 * 64 + j];
            a4 += hs[(size_t)s4 * 64 + j];
            a5 += hs[(size_t)s5 * 64 + j];
            a6 += hs[(size_t)s6 * 64 + j];
            a7 += hs[(size_t)s7 * 64 + j];
        }
        if (p + 4 <= p1) {
            int s0 = csr_src[p], s1 = csr_src[p + 1], s2 = csr_src[p + 2], s3 = csr_src[p + 3];
            a4 += hs[(size_t)s0 * 64 + j];
            a5 += hs[(size_t)s1 * 64 + j];
            a6 += hs[(size_t)s2 * 64 + j];
            a7 += hs[(size_t)s3 * 64 + j];
            p += 4;
        }
        for (; p < p1; ++p) a1 += hs[(size_t)csr_src[p] * 64 + j];
        float a = ((a0 + a1) + (a2 + a3)) + ((a4 + a5) + (a6 + a7));
        di = dinv[w];
        v = fmaxf(a * di + b[j], 0.f);
        h[(size_t)w * 64 + j] = v;
        float t0 = v * wv0[j];
#pragma unroll
        for (int o = 32; o; o >>= 1) t0 += __shfl_xor(t0, o, 64);
        if (j == 0) s0_src[w] = t0 * di;
        if (NDOT == 2) {
            float t1 = v * wv1[j];
#pragma unroll
            for (int o = 32; o; o >>= 1) t1 += __shfl_xor(t1, o, 64);
            if (j == 0) s1_src[w] = t1 * di;
        }
    }
    if (FUSE) {
        __syncthreads();
        if (valid) {
            float a2 = 0.f;
#pragma unroll 8
            for (int jj = 0; jj < 64; ++jj) {
                float vj = __shfl(v, jj, 64);  // loop-uniform -> readlane
                a2 += vj * Wnl[jj * 64 + j];
            }
            hs_next[(size_t)w * 64 + j] = a2 * di;
        }
    }
}

// ---------------- conv3 (64->1): scalar gather -> h3, u_src ----------------
__global__ void psg_h3g(const float* __restrict__ sc_src,
                        const int* __restrict__ rowptr, const int* __restrict__ csr_src,
                        const float* __restrict__ dinv, const float* __restrict__ b3,
                        const float* __restrict__ Ws3,
                        float* __restrict__ h3, float* __restrict__ u_src, int n) {
    int i = blockIdx.x * blockDim.x + threadIdx.x;
    if (i < n) {
        float a = sc_src[i];
        int p1 = rowptr[i + 1];
        for (int p = rowptr[i]; p < p1; ++p) a += sc_src[csr_src[p]];
        float di = dinv[i];
        float v = fmaxf(a * di + b3[0], 0.f);
        h3[i] = v;
        u_src[i] = v * Ws3[0] * di;
    }
}

// ---------------- sort-pool + CNN head fused, one block per graph ----------------
// JAX lax.sort uses a float->int total-order transform, so -0.0 < +0.0 STRICTLY.
__device__ __forceinline__ int psg_f2ord(float f) {
    int s = __float_as_int(f);
    return s < 0 ? (s ^ 0x7fffffff) : s;
}

__global__ __launch_bounds__(128) void psg_spcnn(const float* __restrict__ u_src,
                                                 const int* __restrict__ rowptr,
                                                 const int* __restrict__ csr_src,
                                                 const float* __restrict__ dinv,
                                                 const float* __restrict__ bs1,
                                                 const float* __restrict__ bs2,
                                                 const float* __restrict__ bs3,
                                                 const float* __restrict__ sA_src,
                                                 const float* __restrict__ sB_src,
                                                 const float* __restrict__ h1,
                                                 const float* __restrict__ h2,
                                                 const float* __restrict__ h3,
                                                 const float* __restrict__ Wc1, const float* __restrict__ bc1,
                                                 const float* __restrict__ Wc2, const float* __restrict__ bc2,
                                                 const float* __restrict__ Wl1, const float* __restrict__ bl1,
                                                 const float* __restrict__ Wl2, const float* __restrict__ bl2,
                                                 float* __restrict__ out) {
    int g = blockIdx.x, t = threadIdx.x;
    __shared__ float pl[KK * 129];       // 15.5 KB
    __shared__ float wc1l[16 * 129];     // 8.2 KB
    __shared__ float wc2l[32 * 16 * 5];  // 10 KB
    __shared__ float key[NPG];
    __shared__ int ord[NPG];
    __shared__ int sel[KK];
    __shared__ float sa[KK], sb[KK];
    __shared__ float c1[16 * KK];
    __shared__ float mp[16 * 15];
    __shared__ float c2s[352];
    __shared__ float hdds[128];
    __shared__ float red[2];
    // stage CNN weights early (overlaps the sort phase)
    for (int i = t; i < 16 * 129; i += 128) wc1l[i] = Wc1[i];
    for (int i = t; i < 32 * 16 * 5; i += 128) wc2l[i] = Wc2[i];
    // ---- sort-pool: x3 key via second-hop scalar gather
    if (t < NPG) {
        int node = g * NPG + t;
        float a = u_src[node];
        int pe = rowptr[node + 1];
        for (int p = rowptr[node]; p < pe; ++p) a += u_src[csr_src[p]];
        float v = (a * dinv[node] + bs3[0]) * h3[node];  // keeps ±0 sign
        key[t] = v;
        ord[t] = psg_f2ord(v);
    }
    __syncthreads();
    if (t < NPG) {
        int v = ord[t];
        int r = 0;
        for (int m = 0; m < NPG; m++) {
            int u = ord[m];
            r += (u > v) || (u == v && m < t);  // stable descending, total order
        }
        if (r < KK) sel[r] = t;
    }
    __syncthreads();
    // scalar score gathers for the 30 selected nodes: t<32 -> conv A (x1), 32<=t<64 -> conv B (x2)
    {
        int r = t & 31;
        if (t < 64 && r < KK) {
            int node = g * NPG + sel[r];
            const float* ssrc = (t < 32) ? sA_src : sB_src;
            float a = ssrc[node];
            int pe = rowptr[node + 1];
            for (int p = rowptr[node]; p < pe; ++p) a += ssrc[csr_src[p]];
            float scl = a * dinv[node] + ((t < 32) ? bs1[0] : bs2[0]);
            if (t < 32) sa[r] = scl; else sb[r] = scl;
        }
    }
    __syncthreads();
    // build pooled tile directly in LDS
    for (int idx = t; idx < KK * 129; idx += 128) {
        int r = idx / 129, c = idx - r * 129;
        int node = g * NPG + sel[r];
        float v;
        if (c < 64) v = sa[r] * h1[(size_t)node * 64 + c];
        else if (c < 128) v = sb[r] * h2[(size_t)node * 64 + (c - 64)];
        else v = key[sel[r]];
        pl[idx] = v;
    }
    __syncthreads();
    // conv1d(1->16, k=129, stride=129) + relu
    for (int idx = t; idx < 16 * KK; idx += 128) {
        int c = idx / KK, k = idx % KK;
        float a = bc1[c];
        for (int d = 0; d < 129; d++) a += pl[k * 129 + d] * wc1l[c * 129 + d];
        c1[c * KK + k] = fmaxf(a, 0.f);
    }
    __syncthreads();
    // maxpool1d(2,2)
    for (int idx = t; idx < 16 * 15; idx += 128) {
        int c = idx / 15, k = idx % 15;
        mp[idx] = fmaxf(c1[c * KK + 2 * k], c1[c * KK + 2 * k + 1]);
    }
    __syncthreads();
    // conv1d(16->32, k=5, valid) + relu
    for (int idx = t; idx < 352; idx += 128) {
        int o = idx / 11, k = idx % 11;
        float a = bc2[o];
        for (int i2 = 0; i2 < 16; i2++) {
#pragma unroll
            for (int k2 = 0; k2 < 5; k2++) a += mp[i2 * 15 + k + k2] * wc2l[(o * 16 + i2) * 5 + k2];
        }
        c2s[o * 11 + k] = fmaxf(a, 0.f);
    }
    __syncthreads();
    // linear 352 -> 128 + relu
    {
        float a = bl1[t];
        const float* wr = Wl1 + (size_t)t * 352;
        for (int f = 0; f < 352; f++) a += c2s[f] * wr[f];
        hdds[t] = fmaxf(a, 0.f);
    }
    __syncthreads();
    // linear 128 -> 1
    float p = hdds[t] * Wl2[t];
#pragma unroll
    for (int o = 32; o; o >>= 1) p += __shfl_xor(p, o, 64);
    if ((t & 63) == 0) red[t >> 6] = p;
    __syncthreads();
    if (t == 0) out[g] = red[0] + red[1] + bl2[0];
}

extern "C" void kernel_launch(void* const* d_in, const int* in_sizes, int n_in,
                              void* d_out, int out_size, void* d_ws, size_t ws_size,
                              hipStream_t stream) {
    const float* x   = (const float*)d_in[0];
    const int*   ei  = (const int*)d_in[1];
    const float* W1  = (const float*)d_in[2];
    const float* b1  = (const float*)d_in[3];
    const float* W2  = (const float*)d_in[4];
    const float* b2  = (const float*)d_in[5];
    const float* W3  = (const float*)d_in[6];
    const float* b3  = (const float*)d_in[7];
    const float* Ws1 = (const float*)d_in[8];
    const float* bs1 = (const float*)d_in[9];
    const float* Ws2 = (const float*)d_in[10];
    const float* bs2 = (const float*)d_in[11];
    const float* Ws3 = (const float*)d_in[12];
    const float* bs3 = (const float*)d_in[13];
    const float* Wc1 = (const float*)d_in[14];
    const float* bc1 = (const float*)d_in[15];
    const float* Wc2 = (const float*)d_in[16];
    const float* bc2 = (const float*)d_in[17];
    const float* Wl1 = (const float*)d_in[18];
    const float* bl1 = (const float*)d_in[19];
    const float* Wl2 = (const float*)d_in[20];
    const float* bl2 = (const float*)d_in[21];
    float* out = (float*)d_out;

    const int n = in_sizes[0] / FIN;      // 50000
    const int e = in_sizes[1] / 2;        // 600000
    const int* src = ei;
    const int* dst = ei + e;
    const int nchunk = (n + SCHUNK - 1) / SCHUNK;  // 49 (<=64)

    // workspace carve-up (~56 MB)
    char* w = (char*)d_ws;
    float* dinv    = (float*)w; w += (size_t)n * 4;
    float* sA_src  = (float*)w; w += (size_t)n * 4;
    float* sB_src  = (float*)w; w += (size_t)n * 4;
    float* sC_src  = (float*)w; w += (size_t)n * 4;
    float* h3      = (float*)w; w += (size_t)n * 4;
    float* u_src   = (float*)w; w += (size_t)n * 4;
    int*   deg     = (int*)w;   w += (size_t)n * 4;
    int*   rowptr  = (int*)w;   w += (size_t)(n + 1) * 4;
    int*   rowfill = (int*)w;   w += (size_t)n * 4;
    int*   csums   = (int*)w;   w += 64 * 4;
    int*   csr_src = (int*)w;   w += (size_t)e * 4;
    float* hs1     = (float*)w; w += (size_t)n * 64 * 4;
    float* hs2     = (float*)w; w += (size_t)n * 64 * 4;
    float* h1      = (float*)w; w += (size_t)n * 64 * 4;
    float* h2      = (float*)w; w += (size_t)n * 64 * 4;

    const int nb_e  = (e + 255) / 256;
    const int nb_n  = (n + 255) / 256;
    const int nb_g  = (n + 15) / 16;
    const int nb_nw = (n * 64 + 255) / 256;  // one wave per node

    // graph prep: deg -> rowptr (scan, fused dinv) -> CSR build
    hipMemsetAsync(deg, 0, (size_t)n * 4, stream);
    psg_deg<<<nb_e, 256, 0, stream>>>(dst, deg, e);
    psg_scan1<<<nchunk, SCHUNK, 0, stream>>>(deg, rowptr, csums, dinv, n);
    psg_scan3<<<nchunk, SCHUNK, 0, stream>>>(rowptr, rowfill, csums, n, e);
    psg_build<<<nb_e, 256, 0, stream>>>(src, dst, rowfill, csr_src, e);

    // ---- conv1: h1 = relu(Ahat (x W1) + b1); dot Ws1 -> sA_src; fused hs2 = (h1 W2)*dinv
    psg_gemm<128><<<nb_g, 256, 0, stream>>>(x, W1, dinv, hs1, n);
    psg_gfin<1, true><<<nb_nw, 256, 0, stream>>>(hs1, rowptr, csr_src, dinv, b1, h1,
                                                 Ws1, sA_src, nullptr, nullptr,
                                                 W2, hs2, n);

    // ---- conv2: h2 = relu(Ahat hs2 + b2); dots Ws2 -> sB, W3 -> sC
    psg_gfin<2, false><<<nb_nw, 256, 0, stream>>>(hs2, rowptr, csr_src, dinv, b2, h2,
                                                  Ws2, sB_src, W3, sC_src,
                                                  nullptr, nullptr, n);

    // ---- conv3 (64->1): scalar gather -> h3, u_src (score conv 1->1 message)
    psg_h3g<<<nb_n, 256, 0, stream>>>(sC_src, rowptr, csr_src, dinv, b3, Ws3, h3, u_src, n);

    // ---- sort-pool + CNN head (fused; pooled tile lives in LDS)
    psg_spcnn<<<GG, 128, 0, stream>>>(u_src, rowptr, csr_src, dinv, bs1, bs2, bs3,
                                      sA_src, sB_src, h1, h2, h3,
                                      Wc1, bc1, Wc2, bc2, Wl1, bl1, Wl2, bl2, out);

    (void)n_in; (void)out_size; (void)ws_size;
}

// Round 7
// 346.225 us; speedup vs baseline: 1.0666x; 1.0666x over previous
//
#include <hip/hip_runtime.h>
#include <hip/hip_bf16.h>

// DGCNN forward: 3×GCNConv(+score convs) -> SortPool(k=30) -> Conv1d stack -> MLP
// Round 6: revert r5's gfin GEMM-fusion (LDS-op bound, +37us); keep spcnn merge + 2-kernel scan.
#define NN 50000
#define EE 600000
#define FIN 128
#define GG 500
#define NPG 100
#define KK 30
#define SCHUNK 1024

// ---------------- graph prep ----------------
__global__ void psg_deg(const int* __restrict__ dst, int* __restrict__ deg, int e) {
    int i = blockIdx.x * blockDim.x + threadIdx.x;
    if (i < e) atomicAdd(&deg[dst[i]], 1);
}

// exclusive scan of deg -> rowptr (chunked, raw chunk totals in csums); dinv = (deg+1)^-1/2
__global__ __launch_bounds__(SCHUNK) void psg_scan1(const int* __restrict__ deg,
                                                    int* __restrict__ rowptr,
                                                    int* __restrict__ csums,
                                                    float* __restrict__ dinv, int n) {
    __shared__ int sm[SCHUNK];
    int t = threadIdx.x;
    int base = blockIdx.x * SCHUNK;
    int v = (base + t < n) ? deg[base + t] : 0;
    sm[t] = v;
    __syncthreads();
    for (int off = 1; off < SCHUNK; off <<= 1) {
        int u = (t >= off) ? sm[t - off] : 0;
        __syncthreads();
        sm[t] += u;
        __syncthreads();
    }
    if (base + t < n) {
        rowptr[base + t] = sm[t] - v;  // exclusive within chunk
        dinv[base + t] = 1.0f / sqrtf((float)(v + 1));
    }
    if (t == SCHUNK - 1) csums[blockIdx.x] = sm[t];
}

// add prefix of csums (computed in-block; nchunk<=64); init rowfill; rowptr[n]=e
__global__ __launch_bounds__(SCHUNK) void psg_scan3(int* __restrict__ rowptr,
                                                    int* __restrict__ rowfill,
                                                    const int* __restrict__ csums,
                                                    int n, int e) {
    __shared__ int soff;
    int t = threadIdx.x;
    if (t < 64) {
        int c = (t < (int)blockIdx.x) ? csums[t] : 0;  // blockIdx.x <= 48 < 64
#pragma unroll
        for (int o = 1; o < 64; o <<= 1) c += __shfl_xor(c, o, 64);
        if (t == 0) soff = c;
    }
    __syncthreads();
    int i = blockIdx.x * SCHUNK + t;
    if (i < n) {
        int v = rowptr[i] + soff;
        rowptr[i] = v;
        rowfill[i] = v;
    }
    if (i == 0) rowptr[n] = e;
}

// bucket edges by dst: csr_src[pos] = src
__global__ void psg_build(const int* __restrict__ src, const int* __restrict__ dst,
                          int* __restrict__ rowfill, int* __restrict__ csr_src, int e) {
    int i = blockIdx.x * blockDim.x + threadIdx.x;
    if (i < e) {
        int pos = atomicAdd(&rowfill[dst[i]], 1);
        csr_src[pos] = src[i];
    }
}

// ---------------- GEMM: hs = (X @ W) * dinv ----------------
template <int KD>
__global__ __launch_bounds__(256) void psg_gemm(const float* __restrict__ X,
                                                const float* __restrict__ W,
                                                const float* __restrict__ dinv,
                                                float* __restrict__ hs, int n) {
    __shared__ __align__(16) float Xl[16][KD];
    __shared__ __align__(16) float WtF[(KD / 4) * 64 * 4];
    int t = threadIdx.x;
    int r0 = blockIdx.x * 16;
    for (int i = t; i < KD * 64; i += 256) {
        int k = i >> 6, j = i & 63;
        WtF[(((k >> 2) * 64 + j) << 2) + (k & 3)] = W[i];
    }
    for (int i4 = t; i4 < 16 * (KD / 4); i4 += 256) {
        int r = i4 / (KD / 4), u = i4 % (KD / 4);
        int row = r0 + r;
        float4 v = make_float4(0.f, 0.f, 0.f, 0.f);
        if (row < n) v = ((const float4*)(X + (size_t)row * KD))[u];
        ((float4*)&Xl[r][0])[u] = v;
    }
    __syncthreads();
    int j = t & 63, q = t >> 6;
    const float4* Wt4 = (const float4*)WtF;
    float a0 = 0.f, a1 = 0.f, a2 = 0.f, a3 = 0.f;
#pragma unroll 4
    for (int u = 0; u < KD / 4; ++u) {
        float4 wv = Wt4[u * 64 + j];
        float4 x0 = *(const float4*)&Xl[q * 4 + 0][u * 4];
        float4 x1 = *(const float4*)&Xl[q * 4 + 1][u * 4];
        float4 x2 = *(const float4*)&Xl[q * 4 + 2][u * 4];
        float4 x3 = *(const float4*)&Xl[q * 4 + 3][u * 4];
        a0 += x0.x * wv.x + x0.y * wv.y + x0.z * wv.z + x0.w * wv.w;
        a1 += x1.x * wv.x + x1.y * wv.y + x1.z * wv.z + x1.w * wv.w;
        a2 += x2.x * wv.x + x2.y * wv.y + x2.z * wv.z + x2.w * wv.w;
        a3 += x3.x * wv.x + x3.y * wv.y + x3.z * wv.z + x3.w * wv.w;
    }
    float av[4] = {a0, a1, a2, a3};
#pragma unroll
    for (int rr = 0; rr < 4; rr++) {
        int row = r0 + q * 4 + rr;
        if (row < n) hs[(size_t)row * 64 + j] = av[rr] * dinv[row];
    }
}

// ---------------- gather + finish: one wave per node, ILP-8 ----------------
// acc = hs[node] + sum_{nbr} hs[nbr]; h = relu(acc*dinv + b); fused 64->1 dots
template <int NDOT>
__global__ __launch_bounds__(256) void psg_gfin(const float* __restrict__ hs,
                                                const int* __restrict__ rowptr,
                                                const int* __restrict__ csr_src,
                                                const float* __restrict__ dinv,
                                                const float* __restrict__ b,
                                                float* __restrict__ h,
                                                const float* __restrict__ wv0,
                                                float* __restrict__ s0_src,
                                                const float* __restrict__ wv1,
                                                float* __restrict__ s1_src, int n) {
    int w = (int)((blockIdx.x * 256 + threadIdx.x) >> 6);
    int j = threadIdx.x & 63;
    if (w >= n) return;
    int p0 = rowptr[w], p1 = rowptr[w + 1];
    float a0 = hs[(size_t)w * 64 + j];  // self loop
    float a1 = 0.f, a2 = 0.f, a3 = 0.f, a4 = 0.f, a5 = 0.f, a6 = 0.f, a7 = 0.f;
    int p = p0;
    for (; p + 8 <= p1; p += 8) {
        int s0 = csr_src[p],     s1 = csr_src[p + 1], s2 = csr_src[p + 2], s3 = csr_src[p + 3];
        int s4 = csr_src[p + 4], s5 = csr_src[p + 5], s6 = csr_src[p + 6], s7 = csr_src[p + 7];
        a0 += hs[(size_t)s0 * 64 + j];
        a1 += hs[(size_t)s1 * 64 + j];
        a2 += hs[(size_t)s2 * 64 + j];
        a3 += hs[(size_t)s3 * 64 + j];
        a4 += hs[(size_t)s4 * 64 + j];
        a5 += hs[(size_t)s5 * 64 + j];
        a6 += hs[(size_t)s6 * 64 + j];
        a7 += hs[(size_t)s7 * 64 + j];
    }
    if (p + 4 <= p1) {
        int s0 = csr_src[p], s1 = csr_src[p + 1], s2 = csr_src[p + 2], s3 = csr_src[p + 3];
        a4 += hs[(size_t)s0 * 64 + j];
        a5 += hs[(size_t)s1 * 64 + j];
        a6 += hs[(size_t)s2 * 64 + j];
        a7 += hs[(size_t)s3 * 64 + j];
        p += 4;
    }
    for (; p < p1; ++p) a1 += hs[(size_t)csr_src[p] * 64 + j];
    float a = ((a0 + a1) + (a2 + a3)) + ((a4 + a5) + (a6 + a7));
    float di = dinv[w];
    float v = fmaxf(a * di + b[j], 0.f);
    h[(size_t)w * 64 + j] = v;
    float t0 = v * wv0[j];
#pragma unroll
    for (int o = 32; o; o >>= 1) t0 += __shfl_xor(t0, o, 64);
    if (j == 0) s0_src[w] = t0 * di;
    if (NDOT == 2) {
        float t1 = v * wv1[j];
#pragma unroll
        for (int o = 32; o; o >>= 1) t1 += __shfl_xor(t1, o, 64);
        if (j == 0) s1_src[w] = t1 * di;
    }
}

// ---------------- conv3 (64->1): scalar gather -> h3, u_src ----------------
__global__ void psg_h3g(const float* __restrict__ sc_src,
                        const int* __restrict__ rowptr, const int* __restrict__ csr_src,
                        const float* __restrict__ dinv, const float* __restrict__ b3,
                        const float* __restrict__ Ws3,
                        float* __restrict__ h3, float* __restrict__ u_src, int n) {
    int i = blockIdx.x * blockDim.x + threadIdx.x;
    if (i < n) {
        float a = sc_src[i];
        int p1 = rowptr[i + 1];
        for (int p = rowptr[i]; p < p1; ++p) a += sc_src[csr_src[p]];
        float di = dinv[i];
        float v = fmaxf(a * di + b3[0], 0.f);
        h3[i] = v;
        u_src[i] = v * Ws3[0] * di;
    }
}

// ---------------- sort-pool + CNN head fused, one block per graph ----------------
// JAX lax.sort uses a float->int total-order transform, so -0.0 < +0.0 STRICTLY.
__device__ __forceinline__ int psg_f2ord(float f) {
    int s = __float_as_int(f);
    return s < 0 ? (s ^ 0x7fffffff) : s;
}

__global__ __launch_bounds__(128) void psg_spcnn(const float* __restrict__ u_src,
                                                 const int* __restrict__ rowptr,
                                                 const int* __restrict__ csr_src,
                                                 const float* __restrict__ dinv,
                                                 const float* __restrict__ bs1,
                                                 const float* __restrict__ bs2,
                                                 const float* __restrict__ bs3,
                                                 const float* __restrict__ sA_src,
                                                 const float* __restrict__ sB_src,
                                                 const float* __restrict__ h1,
                                                 const float* __restrict__ h2,
                                                 const float* __restrict__ h3,
                                                 const float* __restrict__ Wc1, const float* __restrict__ bc1,
                                                 const float* __restrict__ Wc2, const float* __restrict__ bc2,
                                                 const float* __restrict__ Wl1, const float* __restrict__ bl1,
                                                 const float* __restrict__ Wl2, const float* __restrict__ bl2,
                                                 float* __restrict__ out) {
    int g = blockIdx.x, t = threadIdx.x;
    __shared__ float pl[KK * 129];
    __shared__ float wc1l[16 * 129];
    __shared__ float wc2l[32 * 16 * 5];
    __shared__ float key[NPG];
    __shared__ int ord[NPG];
    __shared__ int sel[KK];
    __shared__ float sa[KK], sb[KK];
    __shared__ float c1[16 * KK];
    __shared__ float mp[16 * 15];
    __shared__ float c2s[352];
    __shared__ float hdds[128];
    __shared__ float red[2];
    // stage CNN weights early (overlaps the sort phase)
    for (int i = t; i < 16 * 129; i += 128) wc1l[i] = Wc1[i];
    for (int i = t; i < 32 * 16 * 5; i += 128) wc2l[i] = Wc2[i];
    // ---- sort-pool: x3 key via second-hop scalar gather
    if (t < NPG) {
        int node = g * NPG + t;
        float a = u_src[node];
        int pe = rowptr[node + 1];
        for (int p = rowptr[node]; p < pe; ++p) a += u_src[csr_src[p]];
        float v = (a * dinv[node] + bs3[0]) * h3[node];  // keeps ±0 sign
        key[t] = v;
        ord[t] = psg_f2ord(v);
    }
    __syncthreads();
    if (t < NPG) {
        int v = ord[t];
        int r = 0;
        for (int m = 0; m < NPG; m++) {
            int u = ord[m];
            r += (u > v) || (u == v && m < t);  // stable descending, total order
        }
        if (r < KK) sel[r] = t;
    }
    __syncthreads();
    // scalar score gathers for the 30 selected nodes: t<32 -> conv A (x1), 32<=t<64 -> conv B (x2)
    {
        int r = t & 31;
        if (t < 64 && r < KK) {
            int node = g * NPG + sel[r];
            const float* ssrc = (t < 32) ? sA_src : sB_src;
            float a = ssrc[node];
            int pe = rowptr[node + 1];
            for (int p = rowptr[node]; p < pe; ++p) a += ssrc[csr_src[p]];
            float scl = a * dinv[node] + ((t < 32) ? bs1[0] : bs2[0]);
            if (t < 32) sa[r] = scl; else sb[r] = scl;
        }
    }
    __syncthreads();
    // build pooled tile directly in LDS
    for (int idx = t; idx < KK * 129; idx += 128) {
        int r = idx / 129, c = idx - r * 129;
        int node = g * NPG + sel[r];
        float v;
        if (c < 64) v = sa[r] * h1[(size_t)node * 64 + c];
        else if (c < 128) v = sb[r] * h2[(size_t)node * 64 + (c - 64)];
        else v = key[sel[r]];
        pl[idx] = v;
    }
    __syncthreads();
    // conv1d(1->16, k=129, stride=129) + relu
    for (int idx = t; idx < 16 * KK; idx += 128) {
        int c = idx / KK, k = idx % KK;
        float a = bc1[c];
        for (int d = 0; d < 129; d++) a += pl[k * 129 + d] * wc1l[c * 129 + d];
        c1[c * KK + k] = fmaxf(a, 0.f);
    }
    __syncthreads();
    // maxpool1d(2,2)
    for (int idx = t; idx < 16 * 15; idx += 128) {
        int c = idx / 15, k = idx % 15;
        mp[idx] = fmaxf(c1[c * KK + 2 * k], c1[c * KK + 2 * k + 1]);
    }
    __syncthreads();
    // conv1d(16->32, k=5, valid) + relu
    for (int idx = t; idx < 352; idx += 128) {
        int o = idx / 11, k = idx % 11;
        float a = bc2[o];
        for (int i2 = 0; i2 < 16; i2++) {
#pragma unroll
            for (int k2 = 0; k2 < 5; k2++) a += mp[i2 * 15 + k + k2] * wc2l[(o * 16 + i2) * 5 + k2];
        }
        c2s[o * 11 + k] = fmaxf(a, 0.f);
    }
    __syncthreads();
    // linear 352 -> 128 + relu
    {
        float a = bl1[t];
        const float* wr = Wl1 + (size_t)t * 352;
        for (int f = 0; f < 352; f++) a += c2s[f] * wr[f];
        hdds[t] = fmaxf(a, 0.f);
    }
    __syncthreads();
    // linear 128 -> 1
    float p = hdds[t] * Wl2[t];
#pragma unroll
    for (int o = 32; o; o >>= 1) p += __shfl_xor(p, o, 64);
    if ((t & 63) == 0) red[t >> 6] = p;
    __syncthreads();
    if (t == 0) out[g] = red[0] + red[1] + bl2[0];
}

extern "C" void kernel_launch(void* const* d_in, const int* in_sizes, int n_in,
                              void* d_out, int out_size, void* d_ws, size_t ws_size,
                              hipStream_t stream) {
    const float* x   = (const float*)d_in[0];
    const int*   ei  = (const int*)d_in[1];
    const float* W1  = (const float*)d_in[2];
    const float* b1  = (const float*)d_in[3];
    const float* W2  = (const float*)d_in[4];
    const float* b2  = (const float*)d_in[5];
    const float* W3  = (const float*)d_in[6];
    const float* b3  = (const float*)d_in[7];
    const float* Ws1 = (const float*)d_in[8];
    const float* bs1 = (const float*)d_in[9];
    const float* Ws2 = (const float*)d_in[10];
    const float* bs2 = (const float*)d_in[11];
    const float* Ws3 = (const float*)d_in[12];
    const float* bs3 = (const float*)d_in[13];
    const float* Wc1 = (const float*)d_in[14];
    const float* bc1 = (const float*)d_in[15];
    const float* Wc2 = (const float*)d_in[16];
    const float* bc2 = (const float*)d_in[17];
    const float* Wl1 = (const float*)d_in[18];
    const float* bl1 = (const float*)d_in[19];
    const float* Wl2 = (const float*)d_in[20];
    const float* bl2 = (const float*)d_in[21];
    float* out = (float*)d_out;

    const int n = in_sizes[0] / FIN;      // 50000
    const int e = in_sizes[1] / 2;        // 600000
    const int* src = ei;
    const int* dst = ei + e;
    const int nchunk = (n + SCHUNK - 1) / SCHUNK;  // 49 (<=64)

    // workspace carve-up (~43 MB)
    char* w = (char*)d_ws;
    float* dinv    = (float*)w; w += (size_t)n * 4;
    float* sA_src  = (float*)w; w += (size_t)n * 4;
    float* sB_src  = (float*)w; w += (size_t)n * 4;
    float* sC_src  = (float*)w; w += (size_t)n * 4;
    float* h3      = (float*)w; w += (size_t)n * 4;
    float* u_src   = (float*)w; w += (size_t)n * 4;
    int*   deg     = (int*)w;   w += (size_t)n * 4;
    int*   rowptr  = (int*)w;   w += (size_t)(n + 1) * 4;
    int*   rowfill = (int*)w;   w += (size_t)n * 4;
    int*   csums   = (int*)w;   w += 64 * 4;
    int*   csr_src = (int*)w;   w += (size_t)e * 4;
    float* hs      = (float*)w; w += (size_t)n * 64 * 4;  // shared by conv1 & conv2 messages
    float* h1      = (float*)w; w += (size_t)n * 64 * 4;
    float* h2      = (float*)w; w += (size_t)n * 64 * 4;

    const int nb_e  = (e + 255) / 256;
    const int nb_n  = (n + 255) / 256;
    const int nb_g  = (n + 15) / 16;
    const int nb_nw = (n * 64 + 255) / 256;  // one wave per node

    // graph prep: deg -> rowptr (scan, fused dinv) -> CSR build
    hipMemsetAsync(deg, 0, (size_t)n * 4, stream);
    psg_deg<<<nb_e, 256, 0, stream>>>(dst, deg, e);
    psg_scan1<<<nchunk, SCHUNK, 0, stream>>>(deg, rowptr, csums, dinv, n);
    psg_scan3<<<nchunk, SCHUNK, 0, stream>>>(rowptr, rowfill, csums, n, e);
    psg_build<<<nb_e, 256, 0, stream>>>(src, dst, rowfill, csr_src, e);

    // ---- conv1: h1 = relu(Ahat (x W1) + b1); dot Ws1 -> sA_src
    psg_gemm<128><<<nb_g, 256, 0, stream>>>(x, W1, dinv, hs, n);
    psg_gfin<1><<<nb_nw, 256, 0, stream>>>(hs, rowptr, csr_src, dinv, b1, h1,
                                           Ws1, sA_src, nullptr, nullptr, n);

    // ---- conv2: h2 = relu(Ahat (h1 W2) + b2); dots Ws2 -> sB, W3 -> sC
    psg_gemm<64><<<nb_g, 256, 0, stream>>>(h1, W2, dinv, hs, n);
    psg_gfin<2><<<nb_nw, 256, 0, stream>>>(hs, rowptr, csr_src, dinv, b2, h2,
                                           Ws2, sB_src, W3, sC_src, n);

    // ---- conv3 (64->1): scalar gather -> h3, u_src (score conv 1->1 message)
    psg_h3g<<<nb_n, 256, 0, stream>>>(sC_src, rowptr, csr_src, dinv, b3, Ws3, h3, u_src, n);

    // ---- sort-pool + CNN head (fused; pooled tile lives in LDS)
    psg_spcnn<<<GG, 128, 0, stream>>>(u_src, rowptr, csr_src, dinv, bs1, bs2, bs3,
                                      sA_src, sB_src, h1, h2, h3,
                                      Wc1, bc1, Wc2, bc2, Wl1, bl1, Wl2, bl2, out);

    (void)n_in; (void)out_size; (void)ws_size;
}

// Round 9
// 345.737 us; speedup vs baseline: 1.0681x; 1.0014x over previous
//
#include <hip/hip_runtime.h>
#include <hip/hip_bf16.h>

// DGCNN forward: 3×GCNConv(+score convs) -> SortPool(k=30) -> Conv1d stack -> MLP
// Round 7 (resubmit): node-parallel gathers (h3g ext + x3g); spcnn = sort + CNN, 256 thr.
#define NN 50000
#define EE 600000
#define FIN 128
#define GG 500
#define NPG 100
#define KK 30
#define SCHUNK 1024

// ---------------- graph prep ----------------
__global__ void psg_deg(const int* __restrict__ dst, int* __restrict__ deg, int e) {
    int i = blockIdx.x * blockDim.x + threadIdx.x;
    if (i < e) atomicAdd(&deg[dst[i]], 1);
}

// exclusive scan of deg -> rowptr (chunked, raw chunk totals in csums); dinv = (deg+1)^-1/2
__global__ __launch_bounds__(SCHUNK) void psg_scan1(const int* __restrict__ deg,
                                                    int* __restrict__ rowptr,
                                                    int* __restrict__ csums,
                                                    float* __restrict__ dinv, int n) {
    __shared__ int sm[SCHUNK];
    int t = threadIdx.x;
    int base = blockIdx.x * SCHUNK;
    int v = (base + t < n) ? deg[base + t] : 0;
    sm[t] = v;
    __syncthreads();
    for (int off = 1; off < SCHUNK; off <<= 1) {
        int u = (t >= off) ? sm[t - off] : 0;
        __syncthreads();
        sm[t] += u;
        __syncthreads();
    }
    if (base + t < n) {
        rowptr[base + t] = sm[t] - v;  // exclusive within chunk
        dinv[base + t] = 1.0f / sqrtf((float)(v + 1));
    }
    if (t == SCHUNK - 1) csums[blockIdx.x] = sm[t];
}

// add prefix of csums (computed in-block; nchunk<=64); init rowfill; rowptr[n]=e
__global__ __launch_bounds__(SCHUNK) void psg_scan3(int* __restrict__ rowptr,
                                                    int* __restrict__ rowfill,
                                                    const int* __restrict__ csums,
                                                    int n, int e) {
    __shared__ int soff;
    int t = threadIdx.x;
    if (t < 64) {
        int c = (t < (int)blockIdx.x) ? csums[t] : 0;  // blockIdx.x <= 48 < 64
#pragma unroll
        for (int o = 1; o < 64; o <<= 1) c += __shfl_xor(c, o, 64);
        if (t == 0) soff = c;
    }
    __syncthreads();
    int i = blockIdx.x * SCHUNK + t;
    if (i < n) {
        int v = rowptr[i] + soff;
        rowptr[i] = v;
        rowfill[i] = v;
    }
    if (i == 0) rowptr[n] = e;
}

// bucket edges by dst: csr_src[pos] = src
__global__ void psg_build(const int* __restrict__ src, const int* __restrict__ dst,
                          int* __restrict__ rowfill, int* __restrict__ csr_src, int e) {
    int i = blockIdx.x * blockDim.x + threadIdx.x;
    if (i < e) {
        int pos = atomicAdd(&rowfill[dst[i]], 1);
        csr_src[pos] = src[i];
    }
}

// ---------------- GEMM: hs = (X @ W) * dinv ----------------
template <int KD>
__global__ __launch_bounds__(256) void psg_gemm(const float* __restrict__ X,
                                                const float* __restrict__ W,
                                                const float* __restrict__ dinv,
                                                float* __restrict__ hs, int n) {
    __shared__ __align__(16) float Xl[16][KD];
    __shared__ __align__(16) float WtF[(KD / 4) * 64 * 4];
    int t = threadIdx.x;
    int r0 = blockIdx.x * 16;
    for (int i = t; i < KD * 64; i += 256) {
        int k = i >> 6, j = i & 63;
        WtF[(((k >> 2) * 64 + j) << 2) + (k & 3)] = W[i];
    }
    for (int i4 = t; i4 < 16 * (KD / 4); i4 += 256) {
        int r = i4 / (KD / 4), u = i4 % (KD / 4);
        int row = r0 + r;
        float4 v = make_float4(0.f, 0.f, 0.f, 0.f);
        if (row < n) v = ((const float4*)(X + (size_t)row * KD))[u];
        ((float4*)&Xl[r][0])[u] = v;
    }
    __syncthreads();
    int j = t & 63, q = t >> 6;
    const float4* Wt4 = (const float4*)WtF;
    float a0 = 0.f, a1 = 0.f, a2 = 0.f, a3 = 0.f;
#pragma unroll 4
    for (int u = 0; u < KD / 4; ++u) {
        float4 wv = Wt4[u * 64 + j];
        float4 x0 = *(const float4*)&Xl[q * 4 + 0][u * 4];
        float4 x1 = *(const float4*)&Xl[q * 4 + 1][u * 4];
        float4 x2 = *(const float4*)&Xl[q * 4 + 2][u * 4];
        float4 x3 = *(const float4*)&Xl[q * 4 + 3][u * 4];
        a0 += x0.x * wv.x + x0.y * wv.y + x0.z * wv.z + x0.w * wv.w;
        a1 += x1.x * wv.x + x1.y * wv.y + x1.z * wv.z + x1.w * wv.w;
        a2 += x2.x * wv.x + x2.y * wv.y + x2.z * wv.z + x2.w * wv.w;
        a3 += x3.x * wv.x + x3.y * wv.y + x3.z * wv.z + x3.w * wv.w;
    }
    float av[4] = {a0, a1, a2, a3};
#pragma unroll
    for (int rr = 0; rr < 4; rr++) {
        int row = r0 + q * 4 + rr;
        if (row < n) hs[(size_t)row * 64 + j] = av[rr] * dinv[row];
    }
}

// ---------------- gather + finish: one wave per node, ILP-8 ----------------
// acc = hs[node] + sum_{nbr} hs[nbr]; h = relu(acc*dinv + b); fused 64->1 dots
template <int NDOT>
__global__ __launch_bounds__(256) void psg_gfin(const float* __restrict__ hs,
                                                const int* __restrict__ rowptr,
                                                const int* __restrict__ csr_src,
                                                const float* __restrict__ dinv,
                                                const float* __restrict__ b,
                                                float* __restrict__ h,
                                                const float* __restrict__ wv0,
                                                float* __restrict__ s0_src,
                                                const float* __restrict__ wv1,
                                                float* __restrict__ s1_src, int n) {
    int w = (int)((blockIdx.x * 256 + threadIdx.x) >> 6);
    int j = threadIdx.x & 63;
    if (w >= n) return;
    int p0 = rowptr[w], p1 = rowptr[w + 1];
    float a0 = hs[(size_t)w * 64 + j];  // self loop
    float a1 = 0.f, a2 = 0.f, a3 = 0.f, a4 = 0.f, a5 = 0.f, a6 = 0.f, a7 = 0.f;
    int p = p0;
    for (; p + 8 <= p1; p += 8) {
        int s0 = csr_src[p],     s1 = csr_src[p + 1], s2 = csr_src[p + 2], s3 = csr_src[p + 3];
        int s4 = csr_src[p + 4], s5 = csr_src[p + 5], s6 = csr_src[p + 6], s7 = csr_src[p + 7];
        a0 += hs[(size_t)s0 * 64 + j];
        a1 += hs[(size_t)s1 * 64 + j];
        a2 += hs[(size_t)s2 * 64 + j];
        a3 += hs[(size_t)s3 * 64 + j];
        a4 += hs[(size_t)s4 * 64 + j];
        a5 += hs[(size_t)s5 * 64 + j];
        a6 += hs[(size_t)s6 * 64 + j];
        a7 += hs[(size_t)s7 * 64 + j];
    }
    if (p + 4 <= p1) {
        int s0 = csr_src[p], s1 = csr_src[p + 1], s2 = csr_src[p + 2], s3 = csr_src[p + 3];
        a4 += hs[(size_t)s0 * 64 + j];
        a5 += hs[(size_t)s1 * 64 + j];
        a6 += hs[(size_t)s2 * 64 + j];
        a7 += hs[(size_t)s3 * 64 + j];
        p += 4;
    }
    for (; p < p1; ++p) a1 += hs[(size_t)csr_src[p] * 64 + j];
    float a = ((a0 + a1) + (a2 + a3)) + ((a4 + a5) + (a6 + a7));
    float di = dinv[w];
    float v = fmaxf(a * di + b[j], 0.f);
    h[(size_t)w * 64 + j] = v;
    float t0 = v * wv0[j];
#pragma unroll
    for (int o = 32; o; o >>= 1) t0 += __shfl_xor(t0, o, 64);
    if (j == 0) s0_src[w] = t0 * di;
    if (NDOT == 2) {
        float t1 = v * wv1[j];
#pragma unroll
        for (int o = 32; o; o >>= 1) t1 += __shfl_xor(t1, o, 64);
        if (j == 0) s1_src[w] = t1 * di;
    }
}

// ---------------- triple scalar gather: sC -> h3,u_src ; sA -> xs1 ; sB -> xs2 ----------------
__global__ void psg_h3g(const float* __restrict__ sC_src,
                        const float* __restrict__ sA_src,
                        const float* __restrict__ sB_src,
                        const int* __restrict__ rowptr, const int* __restrict__ csr_src,
                        const float* __restrict__ dinv, const float* __restrict__ b3,
                        const float* __restrict__ Ws3,
                        const float* __restrict__ bs1, const float* __restrict__ bs2,
                        float* __restrict__ h3, float* __restrict__ u_src,
                        float* __restrict__ xs1, float* __restrict__ xs2, int n) {
    int i = blockIdx.x * blockDim.x + threadIdx.x;
    if (i < n) {
        float aC = sC_src[i], aA = sA_src[i], aB = sB_src[i];
        int p1 = rowptr[i + 1];
        for (int p = rowptr[i]; p < p1; ++p) {
            int s = csr_src[p];
            aC += sC_src[s];
            aA += sA_src[s];
            aB += sB_src[s];
        }
        float di = dinv[i];
        float v = fmaxf(aC * di + b3[0], 0.f);
        h3[i] = v;
        u_src[i] = v * Ws3[0] * di;
        xs1[i] = aA * di + bs1[0];
        xs2[i] = aB * di + bs2[0];
    }
}

// ---------------- second-hop scalar gather: u_src -> x3 ----------------
__global__ void psg_x3g(const float* __restrict__ u_src,
                        const int* __restrict__ rowptr, const int* __restrict__ csr_src,
                        const float* __restrict__ dinv, const float* __restrict__ bs3,
                        const float* __restrict__ h3, float* __restrict__ x3, int n) {
    int i = blockIdx.x * blockDim.x + threadIdx.x;
    if (i < n) {
        float a = u_src[i];
        int p1 = rowptr[i + 1];
        for (int p = rowptr[i]; p < p1; ++p) a += u_src[csr_src[p]];
        x3[i] = (a * dinv[i] + bs3[0]) * h3[i];  // keeps ±0 sign
    }
}

// ---------------- sort-pool + CNN head fused, one block (256 thr) per graph ----------------
// JAX lax.sort uses a float->int total-order transform, so -0.0 < +0.0 STRICTLY.
__device__ __forceinline__ int psg_f2ord(float f) {
    int s = __float_as_int(f);
    return s < 0 ? (s ^ 0x7fffffff) : s;
}

__global__ __launch_bounds__(256) void psg_spcnn(const float* __restrict__ x3,
                                                 const float* __restrict__ xs1,
                                                 const float* __restrict__ xs2,
                                                 const float* __restrict__ h1,
                                                 const float* __restrict__ h2,
                                                 const float* __restrict__ Wc1, const float* __restrict__ bc1,
                                                 const float* __restrict__ Wc2, const float* __restrict__ bc2,
                                                 const float* __restrict__ Wl1, const float* __restrict__ bl1,
                                                 const float* __restrict__ Wl2, const float* __restrict__ bl2,
                                                 float* __restrict__ out) {
    int g = blockIdx.x, t = threadIdx.x;
    __shared__ float pl[KK * 129];
    __shared__ float wc1l[16 * 129];
    __shared__ float wc2l[32 * 16 * 5];
    __shared__ float key[NPG];
    __shared__ int ord[NPG];
    __shared__ int sel[KK];
    __shared__ float sa[KK], sb[KK];
    __shared__ float c1[16 * KK];
    __shared__ float mp[16 * 15];
    __shared__ float c2s[352];
    __shared__ float hdds[128];
    __shared__ float red[2];
    // stage CNN weights early (overlaps the sort phase)
    for (int i = t; i < 16 * 129; i += 256) wc1l[i] = Wc1[i];
    for (int i = t; i < 32 * 16 * 5; i += 256) wc2l[i] = Wc2[i];
    // ---- sort keys (coalesced read; gathers already done upstream)
    if (t < NPG) {
        float v = x3[g * NPG + t];
        key[t] = v;
        ord[t] = psg_f2ord(v);
    }
    __syncthreads();
    if (t < NPG) {
        int v = ord[t];
        int r = 0;
        for (int m = 0; m < NPG; m++) {
            int u = ord[m];
            r += (u > v) || (u == v && m < t);  // stable descending, total order
        }
        if (r < KK) sel[r] = t;
    }
    __syncthreads();
    // stage selected score scalars
    if (t < KK) sa[t] = xs1[g * NPG + sel[t]];
    else if (t >= 32 && t < 32 + KK) sb[t - 32] = xs2[g * NPG + sel[t - 32]];
    __syncthreads();
    // build pooled tile directly in LDS
    for (int idx = t; idx < KK * 129; idx += 256) {
        int r = idx / 129, c = idx - r * 129;
        int node = g * NPG + sel[r];
        float v;
        if (c < 64) v = sa[r] * h1[(size_t)node * 64 + c];
        else if (c < 128) v = sb[r] * h2[(size_t)node * 64 + (c - 64)];
        else v = key[sel[r]];
        pl[idx] = v;
    }
    __syncthreads();
    // conv1d(1->16, k=129, stride=129) + relu
    for (int idx = t; idx < 16 * KK; idx += 256) {
        int c = idx / KK, k = idx % KK;
        float a = bc1[c];
        for (int d = 0; d < 129; d++) a += pl[k * 129 + d] * wc1l[c * 129 + d];
        c1[c * KK + k] = fmaxf(a, 0.f);
    }
    __syncthreads();
    // maxpool1d(2,2)
    for (int idx = t; idx < 16 * 15; idx += 256) {
        int c = idx / 15, k = idx % 15;
        mp[idx] = fmaxf(c1[c * KK + 2 * k], c1[c * KK + 2 * k + 1]);
    }
    __syncthreads();
    // conv1d(16->32, k=5, valid) + relu
    for (int idx = t; idx < 352; idx += 256) {
        int o = idx / 11, k = idx % 11;
        float a = bc2[o];
        for (int i2 = 0; i2 < 16; i2++) {
#pragma unroll
            for (int k2 = 0; k2 < 5; k2++) a += mp[i2 * 15 + k + k2] * wc2l[(o * 16 + i2) * 5 + k2];
        }
        c2s[o * 11 + k] = fmaxf(a, 0.f);
    }
    __syncthreads();
    // linear 352 -> 128 + relu
    if (t < 128) {
        float a = bl1[t];
        const float* wr = Wl1 + (size_t)t * 352;
        for (int f = 0; f < 352; f++) a += c2s[f] * wr[f];
        hdds[t] = fmaxf(a, 0.f);
    }
    __syncthreads();
    // linear 128 -> 1
    if (t < 128) {
        float p = hdds[t] * Wl2[t];
#pragma unroll
        for (int o = 32; o; o >>= 1) p += __shfl_xor(p, o, 64);
        if ((t & 63) == 0) red[t >> 6] = p;
    }
    __syncthreads();
    if (t == 0) out[g] = red[0] + red[1] + bl2[0];
}

extern "C" void kernel_launch(void* const* d_in, const int* in_sizes, int n_in,
                              void* d_out, int out_size, void* d_ws, size_t ws_size,
                              hipStream_t stream) {
    const float* x   = (const float*)d_in[0];
    const int*   ei  = (const int*)d_in[1];
    const float* W1  = (const float*)d_in[2];
    const float* b1  = (const float*)d_in[3];
    const float* W2  = (const float*)d_in[4];
    const float* b2  = (const float*)d_in[5];
    const float* W3  = (const float*)d_in[6];
    const float* b3  = (const float*)d_in[7];
    const float* Ws1 = (const float*)d_in[8];
    const float* bs1 = (const float*)d_in[9];
    const float* Ws2 = (const float*)d_in[10];
    const float* bs2 = (const float*)d_in[11];
    const float* Ws3 = (const float*)d_in[12];
    const float* bs3 = (const float*)d_in[13];
    const float* Wc1 = (const float*)d_in[14];
    const float* bc1 = (const float*)d_in[15];
    const float* Wc2 = (const float*)d_in[16];
    const float* bc2 = (const float*)d_in[17];
    const float* Wl1 = (const float*)d_in[18];
    const float* bl1 = (const float*)d_in[19];
    const float* Wl2 = (const float*)d_in[20];
    const float* bl2 = (const float*)d_in[21];
    float* out = (float*)d_out;

    const int n = in_sizes[0] / FIN;      // 50000
    const int e = in_sizes[1] / 2;        // 600000
    const int* src = ei;
    const int* dst = ei + e;
    const int nchunk = (n + SCHUNK - 1) / SCHUNK;  // 49 (<=64)

    // workspace carve-up (~44 MB)
    char* w = (char*)d_ws;
    float* dinv    = (float*)w; w += (size_t)n * 4;
    float* sA_src  = (float*)w; w += (size_t)n * 4;
    float* sB_src  = (float*)w; w += (size_t)n * 4;
    float* sC_src  = (float*)w; w += (size_t)n * 4;
    float* h3      = (float*)w; w += (size_t)n * 4;
    float* u_src   = (float*)w; w += (size_t)n * 4;
    float* xs1     = (float*)w; w += (size_t)n * 4;
    float* xs2     = (float*)w; w += (size_t)n * 4;
    float* x3      = (float*)w; w += (size_t)n * 4;
    int*   deg     = (int*)w;   w += (size_t)n * 4;
    int*   rowptr  = (int*)w;   w += (size_t)(n + 1) * 4;
    int*   rowfill = (int*)w;   w += (size_t)n * 4;
    int*   csums   = (int*)w;   w += 64 * 4;
    int*   csr_src = (int*)w;   w += (size_t)e * 4;
    float* hs      = (float*)w; w += (size_t)n * 64 * 4;  // shared by conv1 & conv2 messages
    float* h1      = (float*)w; w += (size_t)n * 64 * 4;
    float* h2      = (float*)w; w += (size_t)n * 64 * 4;

    const int nb_e  = (e + 255) / 256;
    const int nb_n  = (n + 255) / 256;
    const int nb_g  = (n + 15) / 16;
    const int nb_nw = (n * 64 + 255) / 256;  // one wave per node

    // graph prep: deg -> rowptr (scan, fused dinv) -> CSR build
    hipMemsetAsync(deg, 0, (size_t)n * 4, stream);
    psg_deg<<<nb_e, 256, 0, stream>>>(dst, deg, e);
    psg_scan1<<<nchunk, SCHUNK, 0, stream>>>(deg, rowptr, csums, dinv, n);
    psg_scan3<<<nchunk, SCHUNK, 0, stream>>>(rowptr, rowfill, csums, n, e);
    psg_build<<<nb_e, 256, 0, stream>>>(src, dst, rowfill, csr_src, e);

    // ---- conv1: h1 = relu(Ahat (x W1) + b1); dot Ws1 -> sA_src
    psg_gemm<128><<<nb_g, 256, 0, stream>>>(x, W1, dinv, hs, n);
    psg_gfin<1><<<nb_nw, 256, 0, stream>>>(hs, rowptr, csr_src, dinv, b1, h1,
                                           Ws1, sA_src, nullptr, nullptr, n);

    // ---- conv2: h2 = relu(Ahat (h1 W2) + b2); dots Ws2 -> sB, W3 -> sC
    psg_gemm<64><<<nb_g, 256, 0, stream>>>(h1, W2, dinv, hs, n);
    psg_gfin<2><<<nb_nw, 256, 0, stream>>>(hs, rowptr, csr_src, dinv, b2, h2,
                                           Ws2, sB_src, W3, sC_src, n);

    // ---- conv3 (64->1) + score-scalar gathers: h3, u_src, xs1, xs2
    psg_h3g<<<nb_n, 256, 0, stream>>>(sC_src, sA_src, sB_src, rowptr, csr_src, dinv,
                                      b3, Ws3, bs1, bs2, h3, u_src, xs1, xs2, n);
    // ---- score conv second hop: x3 for all nodes
    psg_x3g<<<nb_n, 256, 0, stream>>>(u_src, rowptr, csr_src, dinv, bs3, h3, x3, n);

    // ---- sort-pool + CNN head (no gathers; pooled tile in LDS)
    psg_spcnn<<<GG, 256, 0, stream>>>(x3, xs1, xs2, h1, h2,
                                      Wc1, bc1, Wc2, bc2, Wl1, bl1, Wl2, bl2, out);

    (void)n_in; (void)out_size; (void)ws_size;
}

// Round 13
// 335.728 us; speedup vs baseline: 1.0999x; 1.0298x over previous
//
#include <hip/hip_runtime.h>
#include <hip/hip_bf16.h>

// DGCNN forward: 3×GCNConv(+score convs) -> SortPool(k=30) -> Conv1d stack -> MLP
// Round 9 (resubmit #4): predicated-tail ILP-8 in gfin; ILP-4 batched scalar gathers (h3g/x3g).
#define NN 50000
#define EE 600000
#define FIN 128
#define GG 500
#define NPG 100
#define KK 30
#define SCHUNK 1024

// ---------------- graph prep ----------------
__global__ void psg_deg(const int* __restrict__ dst, int* __restrict__ deg, int e) {
    int i = blockIdx.x * blockDim.x + threadIdx.x;
    if (i < e) atomicAdd(&deg[dst[i]], 1);
}

// exclusive scan of deg -> rowptr (chunked, raw chunk totals in csums); dinv = (deg+1)^-1/2
__global__ __launch_bounds__(SCHUNK) void psg_scan1(const int* __restrict__ deg,
                                                    int* __restrict__ rowptr,
                                                    int* __restrict__ csums,
                                                    float* __restrict__ dinv, int n) {
    __shared__ int sm[SCHUNK];
    int t = threadIdx.x;
    int base = blockIdx.x * SCHUNK;
    int v = (base + t < n) ? deg[base + t] : 0;
    sm[t] = v;
    __syncthreads();
    for (int off = 1; off < SCHUNK; off <<= 1) {
        int u = (t >= off) ? sm[t - off] : 0;
        __syncthreads();
        sm[t] += u;
        __syncthreads();
    }
    if (base + t < n) {
        rowptr[base + t] = sm[t] - v;  // exclusive within chunk
        dinv[base + t] = 1.0f / sqrtf((float)(v + 1));
    }
    if (t == SCHUNK - 1) csums[blockIdx.x] = sm[t];
}

// add prefix of csums (computed in-block; nchunk<=64); init rowfill; rowptr[n]=e
__global__ __launch_bounds__(SCHUNK) void psg_scan3(int* __restrict__ rowptr,
                                                    int* __restrict__ rowfill,
                                                    const int* __restrict__ csums,
                                                    int n, int e) {
    __shared__ int soff;
    int t = threadIdx.x;
    if (t < 64) {
        int c = (t < (int)blockIdx.x) ? csums[t] : 0;  // blockIdx.x <= 48 < 64
#pragma unroll
        for (int o = 1; o < 64; o <<= 1) c += __shfl_xor(c, o, 64);
        if (t == 0) soff = c;
    }
    __syncthreads();
    int i = blockIdx.x * SCHUNK + t;
    if (i < n) {
        int v = rowptr[i] + soff;
        rowptr[i] = v;
        rowfill[i] = v;
    }
    if (i == 0) rowptr[n] = e;
}

// bucket edges by dst: csr_src[pos] = src
__global__ void psg_build(const int* __restrict__ src, const int* __restrict__ dst,
                          int* __restrict__ rowfill, int* __restrict__ csr_src, int e) {
    int i = blockIdx.x * blockDim.x + threadIdx.x;
    if (i < e) {
        int pos = atomicAdd(&rowfill[dst[i]], 1);
        csr_src[pos] = src[i];
    }
}

// ---------------- GEMM: hs = (X @ W) * dinv ----------------
template <int KD>
__global__ __launch_bounds__(256) void psg_gemm(const float* __restrict__ X,
                                                const float* __restrict__ W,
                                                const float* __restrict__ dinv,
                                                float* __restrict__ hs, int n) {
    __shared__ __align__(16) float Xl[16][KD];
    __shared__ __align__(16) float WtF[(KD / 4) * 64 * 4];
    int t = threadIdx.x;
    int r0 = blockIdx.x * 16;
    for (int i = t; i < KD * 64; i += 256) {
        int k = i >> 6, j = i & 63;
        WtF[(((k >> 2) * 64 + j) << 2) + (k & 3)] = W[i];
    }
    for (int i4 = t; i4 < 16 * (KD / 4); i4 += 256) {
        int r = i4 / (KD / 4), u = i4 % (KD / 4);
        int row = r0 + r;
        float4 v = make_float4(0.f, 0.f, 0.f, 0.f);
        if (row < n) v = ((const float4*)(X + (size_t)row * KD))[u];
        ((float4*)&Xl[r][0])[u] = v;
    }
    __syncthreads();
    int j = t & 63, q = t >> 6;
    const float4* Wt4 = (const float4*)WtF;
    float a0 = 0.f, a1 = 0.f, a2 = 0.f, a3 = 0.f;
#pragma unroll 4
    for (int u = 0; u < KD / 4; ++u) {
        float4 wv = Wt4[u * 64 + j];
        float4 x0 = *(const float4*)&Xl[q * 4 + 0][u * 4];
        float4 x1 = *(const float4*)&Xl[q * 4 + 1][u * 4];
        float4 x2 = *(const float4*)&Xl[q * 4 + 2][u * 4];
        float4 x3 = *(const float4*)&Xl[q * 4 + 3][u * 4];
        a0 += x0.x * wv.x + x0.y * wv.y + x0.z * wv.z + x0.w * wv.w;
        a1 += x1.x * wv.x + x1.y * wv.y + x1.z * wv.z + x1.w * wv.w;
        a2 += x2.x * wv.x + x2.y * wv.y + x2.z * wv.z + x2.w * wv.w;
        a3 += x3.x * wv.x + x3.y * wv.y + x3.z * wv.z + x3.w * wv.w;
    }
    float av[4] = {a0, a1, a2, a3};
#pragma unroll
    for (int rr = 0; rr < 4; rr++) {
        int row = r0 + q * 4 + rr;
        if (row < n) hs[(size_t)row * 64 + j] = av[rr] * dinv[row];
    }
}

// ---------------- gather + finish: one wave per node, ILP-8 + predicated tail ----------------
// acc = hs[node] + sum_{nbr} hs[nbr]; h = relu(acc*dinv + b); fused 64->1 dots
template <int NDOT>
__global__ __launch_bounds__(256) void psg_gfin(const float* __restrict__ hs,
                                                const int* __restrict__ rowptr,
                                                const int* __restrict__ csr_src,
                                                const float* __restrict__ dinv,
                                                const float* __restrict__ b,
                                                float* __restrict__ h,
                                                const float* __restrict__ wv0,
                                                float* __restrict__ s0_src,
                                                const float* __restrict__ wv1,
                                                float* __restrict__ s1_src, int n) {
    int w = (int)((blockIdx.x * 256 + threadIdx.x) >> 6);
    int j = threadIdx.x & 63;
    if (w >= n) return;
    int p0 = rowptr[w], p1 = rowptr[w + 1];
    float a0 = hs[(size_t)w * 64 + j];  // self loop
    float a1 = 0.f, a2 = 0.f, a3 = 0.f, a4 = 0.f, a5 = 0.f, a6 = 0.f, a7 = 0.f;
    int p = p0;
    for (; p + 8 <= p1; p += 8) {
        int s0 = csr_src[p],     s1 = csr_src[p + 1], s2 = csr_src[p + 2], s3 = csr_src[p + 3];
        int s4 = csr_src[p + 4], s5 = csr_src[p + 5], s6 = csr_src[p + 6], s7 = csr_src[p + 7];
        a0 += hs[(size_t)s0 * 64 + j];
        a1 += hs[(size_t)s1 * 64 + j];
        a2 += hs[(size_t)s2 * 64 + j];
        a3 += hs[(size_t)s3 * 64 + j];
        a4 += hs[(size_t)s4 * 64 + j];
        a5 += hs[(size_t)s5 * 64 + j];
        a6 += hs[(size_t)s6 * 64 + j];
        a7 += hs[(size_t)s7 * 64 + j];
    }
    int rem = p1 - p;  // 0..7
    if (rem > 0) {
        // predicated full-width tail: clamped indices -> all loads independent;
        // clamped duplicates hit the same line (L1), masked out of the sum.
        int c = p1 - 1;
        int s0 = csr_src[p];
        int s1 = csr_src[(p + 1 < p1) ? p + 1 : c];
        int s2 = csr_src[(p + 2 < p1) ? p + 2 : c];
        int s3 = csr_src[(p + 3 < p1) ? p + 3 : c];
        int s4 = csr_src[(p + 4 < p1) ? p + 4 : c];
        int s5 = csr_src[(p + 5 < p1) ? p + 5 : c];
        int s6 = csr_src[(p + 6 < p1) ? p + 6 : c];
        a0 += hs[(size_t)s0 * 64 + j];
        a1 += (rem > 1) ? hs[(size_t)s1 * 64 + j] : 0.f;
        a2 += (rem > 2) ? hs[(size_t)s2 * 64 + j] : 0.f;
        a3 += (rem > 3) ? hs[(size_t)s3 * 64 + j] : 0.f;
        a4 += (rem > 4) ? hs[(size_t)s4 * 64 + j] : 0.f;
        a5 += (rem > 5) ? hs[(size_t)s5 * 64 + j] : 0.f;
        a6 += (rem > 6) ? hs[(size_t)s6 * 64 + j] : 0.f;
    }
    float a = ((a0 + a1) + (a2 + a3)) + ((a4 + a5) + (a6 + a7));
    float di = dinv[w];
    float v = fmaxf(a * di + b[j], 0.f);
    h[(size_t)w * 64 + j] = v;
    float t0 = v * wv0[j];
#pragma unroll
    for (int o = 32; o; o >>= 1) t0 += __shfl_xor(t0, o, 64);
    if (j == 0) s0_src[w] = t0 * di;
    if (NDOT == 2) {
        float t1 = v * wv1[j];
#pragma unroll
        for (int o = 32; o; o >>= 1) t1 += __shfl_xor(t1, o, 64);
        if (j == 0) s1_src[w] = t1 * di;
    }
}

// ---------------- triple scalar gather (ILP-4 batched): sC -> h3,u_src ; sA -> xs1 ; sB -> xs2 ----
__global__ void psg_h3g(const float* __restrict__ sC_src,
                        const float* __restrict__ sA_src,
                        const float* __restrict__ sB_src,
                        const int* __restrict__ rowptr, const int* __restrict__ csr_src,
                        const float* __restrict__ dinv, const float* __restrict__ b3,
                        const float* __restrict__ Ws3,
                        const float* __restrict__ bs1, const float* __restrict__ bs2,
                        float* __restrict__ h3, float* __restrict__ u_src,
                        float* __restrict__ xs1, float* __restrict__ xs2, int n) {
    int i = blockIdx.x * blockDim.x + threadIdx.x;
    if (i >= n) return;
    float aC = sC_src[i], aA = sA_src[i], aB = sB_src[i];
    float c1 = 0.f, c2 = 0.f, c3 = 0.f;
    float A1 = 0.f, A2 = 0.f, A3 = 0.f;
    float B1 = 0.f, B2 = 0.f, B3 = 0.f;
    int p = rowptr[i], p1 = rowptr[i + 1];
    for (; p + 4 <= p1; p += 4) {
        int s0 = csr_src[p], s1 = csr_src[p + 1], s2 = csr_src[p + 2], s3 = csr_src[p + 3];
        aC += sC_src[s0]; c1 += sC_src[s1]; c2 += sC_src[s2]; c3 += sC_src[s3];
        aA += sA_src[s0]; A1 += sA_src[s1]; A2 += sA_src[s2]; A3 += sA_src[s3];
        aB += sB_src[s0]; B1 += sB_src[s1]; B2 += sB_src[s2]; B3 += sB_src[s3];
    }
    int rem = p1 - p;  // 0..3
    if (rem > 0) {
        int c = p1 - 1;
        int s0 = csr_src[p];
        int s1 = csr_src[(p + 1 < p1) ? p + 1 : c];
        int s2 = csr_src[(p + 2 < p1) ? p + 2 : c];
        aC += sC_src[s0]; aA += sA_src[s0]; aB += sB_src[s0];
        if (rem > 1) { c1 += sC_src[s1]; A1 += sA_src[s1]; B1 += sB_src[s1]; }
        if (rem > 2) { c2 += sC_src[s2]; A2 += sA_src[s2]; B2 += sB_src[s2]; }
    }
    aC += (c1 + c2) + c3;
    aA += (A1 + A2) + A3;
    aB += (B1 + B2) + B3;
    float di = dinv[i];
    float v = fmaxf(aC * di + b3[0], 0.f);
    h3[i] = v;
    u_src[i] = v * Ws3[0] * di;
    xs1[i] = aA * di + bs1[0];
    xs2[i] = aB * di + bs2[0];
}

// ---------------- second-hop scalar gather (ILP-4 batched): u_src -> x3 ----------------
__global__ void psg_x3g(const float* __restrict__ u_src,
                        const int* __restrict__ rowptr, const int* __restrict__ csr_src,
                        const float* __restrict__ dinv, const float* __restrict__ bs3,
                        const float* __restrict__ h3, float* __restrict__ x3, int n) {
    int i = blockIdx.x * blockDim.x + threadIdx.x;
    if (i >= n) return;
    float a = u_src[i], u1 = 0.f, u2 = 0.f, u3 = 0.f;
    int p = rowptr[i], p1 = rowptr[i + 1];
    for (; p + 4 <= p1; p += 4) {
        int s0 = csr_src[p], s1 = csr_src[p + 1], s2 = csr_src[p + 2], s3 = csr_src[p + 3];
        a += u_src[s0]; u1 += u_src[s1]; u2 += u_src[s2]; u3 += u_src[s3];
    }
    int rem = p1 - p;
    if (rem > 0) {
        int c = p1 - 1;
        int s0 = csr_src[p];
        int s1 = csr_src[(p + 1 < p1) ? p + 1 : c];
        int s2 = csr_src[(p + 2 < p1) ? p + 2 : c];
        a += u_src[s0];
        if (rem > 1) u1 += u_src[s1];
        if (rem > 2) u2 += u_src[s2];
    }
    a += (u1 + u2) + u3;
    x3[i] = (a * dinv[i] + bs3[0]) * h3[i];  // keeps ±0 sign
}

// ---------------- sort-pool + CNN head fused, one block (256 thr) per graph ----------------
// JAX lax.sort uses a float->int total-order transform, so -0.0 < +0.0 STRICTLY.
__device__ __forceinline__ int psg_f2ord(float f) {
    int s = __float_as_int(f);
    return s < 0 ? (s ^ 0x7fffffff) : s;
}

__global__ __launch_bounds__(256) void psg_spcnn(const float* __restrict__ x3,
                                                 const float* __restrict__ xs1,
                                                 const float* __restrict__ xs2,
                                                 const float* __restrict__ h1,
                                                 const float* __restrict__ h2,
                                                 const float* __restrict__ Wc1, const float* __restrict__ bc1,
                                                 const float* __restrict__ Wc2, const float* __restrict__ bc2,
                                                 const float* __restrict__ Wl1, const float* __restrict__ bl1,
                                                 const float* __restrict__ Wl2, const float* __restrict__ bl2,
                                                 float* __restrict__ out) {
    int g = blockIdx.x, t = threadIdx.x;
    __shared__ float pl[KK * 129];
    __shared__ float wc1l[16 * 129];
    __shared__ float wc2l[32 * 16 * 5];
    __shared__ float key[NPG];
    __shared__ int ord[NPG];
    __shared__ int sel[KK];
    __shared__ float sa[KK], sb[KK];
    __shared__ float c1[16 * KK];
    __shared__ float mp[16 * 15];
    __shared__ float c2s[352];
    __shared__ float hdds[128];
    __shared__ float red[2];
    // stage CNN weights early (overlaps the sort phase)
    for (int i = t; i < 16 * 129; i += 256) wc1l[i] = Wc1[i];
    for (int i = t; i < 32 * 16 * 5; i += 256) wc2l[i] = Wc2[i];
    // ---- sort keys (coalesced read; gathers already done upstream)
    if (t < NPG) {
        float v = x3[g * NPG + t];
        key[t] = v;
        ord[t] = psg_f2ord(v);
    }
    __syncthreads();
    if (t < NPG) {
        int v = ord[t];
        int r = 0;
        for (int m = 0; m < NPG; m++) {
            int u = ord[m];
            r += (u > v) || (u == v && m < t);  // stable descending, total order
        }
        if (r < KK) sel[r] = t;
    }
    __syncthreads();
    // stage selected score scalars
    if (t < KK) sa[t] = xs1[g * NPG + sel[t]];
    else if (t >= 32 && t < 32 + KK) sb[t - 32] = xs2[g * NPG + sel[t - 32]];
    __syncthreads();
    // build pooled tile directly in LDS
    for (int idx = t; idx < KK * 129; idx += 256) {
        int r = idx / 129, c = idx - r * 129;
        int node = g * NPG + sel[r];
        float v;
        if (c < 64) v = sa[r] * h1[(size_t)node * 64 + c];
        else if (c < 128) v = sb[r] * h2[(size_t)node * 64 + (c - 64)];
        else v = key[sel[r]];
        pl[idx] = v;
    }
    __syncthreads();
    // conv1d(1->16, k=129, stride=129) + relu
    for (int idx = t; idx < 16 * KK; idx += 256) {
        int c = idx / KK, k = idx % KK;
        float a = bc1[c];
        for (int d = 0; d < 129; d++) a += pl[k * 129 + d] * wc1l[c * 129 + d];
        c1[c * KK + k] = fmaxf(a, 0.f);
    }
    __syncthreads();
    // maxpool1d(2,2)
    for (int idx = t; idx < 16 * 15; idx += 256) {
        int c = idx / 15, k = idx % 15;
        mp[idx] = fmaxf(c1[c * KK + 2 * k], c1[c * KK + 2 * k + 1]);
    }
    __syncthreads();
    // conv1d(16->32, k=5, valid) + relu
    for (int idx = t; idx < 352; idx += 256) {
        int o = idx / 11, k = idx % 11;
        float a = bc2[o];
        for (int i2 = 0; i2 < 16; i2++) {
#pragma unroll
            for (int k2 = 0; k2 < 5; k2++) a += mp[i2 * 15 + k + k2] * wc2l[(o * 16 + i2) * 5 + k2];
        }
        c2s[o * 11 + k] = fmaxf(a, 0.f);
    }
    __syncthreads();
    // linear 352 -> 128 + relu
    if (t < 128) {
        float a = bl1[t];
        const float* wr = Wl1 + (size_t)t * 352;
        for (int f = 0; f < 352; f++) a += c2s[f] * wr[f];
        hdds[t] = fmaxf(a, 0.f);
    }
    __syncthreads();
    // linear 128 -> 1
    if (t < 128) {
        float p = hdds[t] * Wl2[t];
#pragma unroll
        for (int o = 32; o; o >>= 1) p += __shfl_xor(p, o, 64);
        if ((t & 63) == 0) red[t >> 6] = p;
    }
    __syncthreads();
    if (t == 0) out[g] = red[0] + red[1] + bl2[0];
}

extern "C" void kernel_launch(void* const* d_in, const int* in_sizes, int n_in,
                              void* d_out, int out_size, void* d_ws, size_t ws_size,
                              hipStream_t stream) {
    const float* x   = (const float*)d_in[0];
    const int*   ei  = (const int*)d_in[1];
    const float* W1  = (const float*)d_in[2];
    const float* b1  = (const float*)d_in[3];
    const float* W2  = (const float*)d_in[4];
    const float* b2  = (const float*)d_in[5];
    const float* W3  = (const float*)d_in[6];
    const float* b3  = (const float*)d_in[7];
    const float* Ws1 = (const float*)d_in[8];
    const float* bs1 = (const float*)d_in[9];
    const float* Ws2 = (const float*)d_in[10];
    const float* bs2 = (const float*)d_in[11];
    const float* Ws3 = (const float*)d_in[12];
    const float* bs3 = (const float*)d_in[13];
    const float* Wc1 = (const float*)d_in[14];
    const float* bc1 = (const float*)d_in[15];
    const float* Wc2 = (const float*)d_in[16];
    const float* bc2 = (const float*)d_in[17];
    const float* Wl1 = (const float*)d_in[18];
    const float* bl1 = (const float*)d_in[19];
    const float* Wl2 = (const float*)d_in[20];
    const float* bl2 = (const float*)d_in[21];
    float* out = (float*)d_out;

    const int n = in_sizes[0] / FIN;      // 50000
    const int e = in_sizes[1] / 2;        // 600000
    const int* src = ei;
    const int* dst = ei + e;
    const int nchunk = (n + SCHUNK - 1) / SCHUNK;  // 49 (<=64)

    // workspace carve-up (~44 MB)
    char* w = (char*)d_ws;
    float* dinv    = (float*)w; w += (size_t)n * 4;
    float* sA_src  = (float*)w; w += (size_t)n * 4;
    float* sB_src  = (float*)w; w += (size_t)n * 4;
    float* sC_src  = (float*)w; w += (size_t)n * 4;
    float* h3      = (float*)w; w += (size_t)n * 4;
    float* u_src   = (float*)w; w += (size_t)n * 4;
    float* xs1     = (float*)w; w += (size_t)n * 4;
    float* xs2     = (float*)w; w += (size_t)n * 4;
    float* x3      = (float*)w; w += (size_t)n * 4;
    int*   deg     = (int*)w;   w += (size_t)n * 4;
    int*   rowptr  = (int*)w;   w += (size_t)(n + 1) * 4;
    int*   rowfill = (int*)w;   w += (size_t)n * 4;
    int*   csums   = (int*)w;   w += 64 * 4;
    int*   csr_src = (int*)w;   w += (size_t)e * 4;
    float* hs      = (float*)w; w += (size_t)n * 64 * 4;  // shared by conv1 & conv2 messages
    float* h1      = (float*)w; w += (size_t)n * 64 * 4;
    float* h2      = (float*)w; w += (size_t)n * 64 * 4;

    const int nb_e  = (e + 255) / 256;
    const int nb_n  = (n + 255) / 256;
    const int nb_g  = (n + 15) / 16;
    const int nb_nw = (n * 64 + 255) / 256;  // one wave per node

    // graph prep: deg -> rowptr (scan, fused dinv) -> CSR build
    hipMemsetAsync(deg, 0, (size_t)n * 4, stream);
    psg_deg<<<nb_e, 256, 0, stream>>>(dst, deg, e);
    psg_scan1<<<nchunk, SCHUNK, 0, stream>>>(deg, rowptr, csums, dinv, n);
    psg_scan3<<<nchunk, SCHUNK, 0, stream>>>(rowptr, rowfill, csums, n, e);
    psg_build<<<nb_e, 256, 0, stream>>>(src, dst, rowfill, csr_src, e);

    // ---- conv1: h1 = relu(Ahat (x W1) + b1); dot Ws1 -> sA_src
    psg_gemm<128><<<nb_g, 256, 0, stream>>>(x, W1, dinv, hs, n);
    psg_gfin<1><<<nb_nw, 256, 0, stream>>>(hs, rowptr, csr_src, dinv, b1, h1,
                                           Ws1, sA_src, nullptr, nullptr, n);

    // ---- conv2: h2 = relu(Ahat (h1 W2) + b2); dots Ws2 -> sB, W3 -> sC
    psg_gemm<64><<<nb_g, 256, 0, stream>>>(h1, W2, dinv, hs, n);
    psg_gfin<2><<<nb_nw, 256, 0, stream>>>(hs, rowptr, csr_src, dinv, b2, h2,
                                           Ws2, sB_src, W3, sC_src, n);

    // ---- conv3 (64->1) + score-scalar gathers: h3, u_src, xs1, xs2
    psg_h3g<<<nb_n, 256, 0, stream>>>(sC_src, sA_src, sB_src, rowptr, csr_src, dinv,
                                      b3, Ws3, bs1, bs2, h3, u_src, xs1, xs2, n);
    // ---- score conv second hop: x3 for all nodes
    psg_x3g<<<nb_n, 256, 0, stream>>>(u_src, rowptr, csr_src, dinv, bs3, h3, x3, n);

    // ---- sort-pool + CNN head (no gathers; pooled tile in LDS)
    psg_spcnn<<<GG, 256, 0, stream>>>(x3, xs1, xs2, h1, h2,
                                      Wc1, bc1, Wc2, bc2, Wl1, bl1, Wl2, bl2, out);

    (void)n_in; (void)out_size; (void)ws_size;
}

// Round 14
// 335.628 us; speedup vs baseline: 1.1003x; 1.0003x over previous
//
#include <hip/hip_runtime.h>
#include <hip/hip_bf16.h>

// DGCNN forward: 3×GCNConv(+score convs) -> SortPool(k=30) -> Conv1d stack -> MLP
// Round 14: 16-wide gfin batches (1 latency round/node); 8-wide h3g; 16-wide x3g;
//           int4-vectorized deg/build.
#define NN 50000
#define EE 600000
#define FIN 128
#define GG 500
#define NPG 100
#define KK 30
#define SCHUNK 1024

// ---------------- graph prep ----------------
__global__ void psg_deg(const int4* __restrict__ dst4, int* __restrict__ deg, int e4) {
    int i = blockIdx.x * blockDim.x + threadIdx.x;
    if (i < e4) {
        int4 d = dst4[i];
        atomicAdd(&deg[d.x], 1);
        atomicAdd(&deg[d.y], 1);
        atomicAdd(&deg[d.z], 1);
        atomicAdd(&deg[d.w], 1);
    }
}

// exclusive scan of deg -> rowptr (chunked, raw chunk totals in csums); dinv = (deg+1)^-1/2
__global__ __launch_bounds__(SCHUNK) void psg_scan1(const int* __restrict__ deg,
                                                    int* __restrict__ rowptr,
                                                    int* __restrict__ csums,
                                                    float* __restrict__ dinv, int n) {
    __shared__ int sm[SCHUNK];
    int t = threadIdx.x;
    int base = blockIdx.x * SCHUNK;
    int v = (base + t < n) ? deg[base + t] : 0;
    sm[t] = v;
    __syncthreads();
    for (int off = 1; off < SCHUNK; off <<= 1) {
        int u = (t >= off) ? sm[t - off] : 0;
        __syncthreads();
        sm[t] += u;
        __syncthreads();
    }
    if (base + t < n) {
        rowptr[base + t] = sm[t] - v;  // exclusive within chunk
        dinv[base + t] = 1.0f / sqrtf((float)(v + 1));
    }
    if (t == SCHUNK - 1) csums[blockIdx.x] = sm[t];
}

// add prefix of csums (computed in-block; nchunk<=64); init rowfill; rowptr[n]=e
__global__ __launch_bounds__(SCHUNK) void psg_scan3(int* __restrict__ rowptr,
                                                    int* __restrict__ rowfill,
                                                    const int* __restrict__ csums,
                                                    int n, int e) {
    __shared__ int soff;
    int t = threadIdx.x;
    if (t < 64) {
        int c = (t < (int)blockIdx.x) ? csums[t] : 0;  // blockIdx.x <= 48 < 64
#pragma unroll
        for (int o = 1; o < 64; o <<= 1) c += __shfl_xor(c, o, 64);
        if (t == 0) soff = c;
    }
    __syncthreads();
    int i = blockIdx.x * SCHUNK + t;
    if (i < n) {
        int v = rowptr[i] + soff;
        rowptr[i] = v;
        rowfill[i] = v;
    }
    if (i == 0) rowptr[n] = e;
}

// bucket edges by dst: csr_src[pos] = src (4 edges/thread, independent atomic chains)
__global__ void psg_build(const int4* __restrict__ src4, const int4* __restrict__ dst4,
                          int* __restrict__ rowfill, int* __restrict__ csr_src, int e4) {
    int i = blockIdx.x * blockDim.x + threadIdx.x;
    if (i < e4) {
        int4 s = src4[i], d = dst4[i];
        int p0 = atomicAdd(&rowfill[d.x], 1);
        int p1 = atomicAdd(&rowfill[d.y], 1);
        int p2 = atomicAdd(&rowfill[d.z], 1);
        int p3 = atomicAdd(&rowfill[d.w], 1);
        csr_src[p0] = s.x;
        csr_src[p1] = s.y;
        csr_src[p2] = s.z;
        csr_src[p3] = s.w;
    }
}

// ---------------- GEMM: hs = (X @ W) * dinv ----------------
template <int KD>
__global__ __launch_bounds__(256) void psg_gemm(const float* __restrict__ X,
                                                const float* __restrict__ W,
                                                const float* __restrict__ dinv,
                                                float* __restrict__ hs, int n) {
    __shared__ __align__(16) float Xl[16][KD];
    __shared__ __align__(16) float WtF[(KD / 4) * 64 * 4];
    int t = threadIdx.x;
    int r0 = blockIdx.x * 16;
    for (int i = t; i < KD * 64; i += 256) {
        int k = i >> 6, j = i & 63;
        WtF[(((k >> 2) * 64 + j) << 2) + (k & 3)] = W[i];
    }
    for (int i4 = t; i4 < 16 * (KD / 4); i4 += 256) {
        int r = i4 / (KD / 4), u = i4 % (KD / 4);
        int row = r0 + r;
        float4 v = make_float4(0.f, 0.f, 0.f, 0.f);
        if (row < n) v = ((const float4*)(X + (size_t)row * KD))[u];
        ((float4*)&Xl[r][0])[u] = v;
    }
    __syncthreads();
    int j = t & 63, q = t >> 6;
    const float4* Wt4 = (const float4*)WtF;
    float a0 = 0.f, a1 = 0.f, a2 = 0.f, a3 = 0.f;
#pragma unroll 4
    for (int u = 0; u < KD / 4; ++u) {
        float4 wv = Wt4[u * 64 + j];
        float4 x0 = *(const float4*)&Xl[q * 4 + 0][u * 4];
        float4 x1 = *(const float4*)&Xl[q * 4 + 1][u * 4];
        float4 x2 = *(const float4*)&Xl[q * 4 + 2][u * 4];
        float4 x3 = *(const float4*)&Xl[q * 4 + 3][u * 4];
        a0 += x0.x * wv.x + x0.y * wv.y + x0.z * wv.z + x0.w * wv.w;
        a1 += x1.x * wv.x + x1.y * wv.y + x1.z * wv.z + x1.w * wv.w;
        a2 += x2.x * wv.x + x2.y * wv.y + x2.z * wv.z + x2.w * wv.w;
        a3 += x3.x * wv.x + x3.y * wv.y + x3.z * wv.z + x3.w * wv.w;
    }
    float av[4] = {a0, a1, a2, a3};
#pragma unroll
    for (int rr = 0; rr < 4; rr++) {
        int row = r0 + q * 4 + rr;
        if (row < n) hs[(size_t)row * 64 + j] = av[rr] * dinv[row];
    }
}

// ---------------- gather + finish: one wave per node, 16-wide batches ----------------
// acc = hs[node] + sum_{nbr} hs[nbr]; h = relu(acc*dinv + b); fused 64->1 dots
template <int NDOT>
__global__ __launch_bounds__(256) void psg_gfin(const float* __restrict__ hs,
                                                const int* __restrict__ rowptr,
                                                const int* __restrict__ csr_src,
                                                const float* __restrict__ dinv,
                                                const float* __restrict__ b,
                                                float* __restrict__ h,
                                                const float* __restrict__ wv0,
                                                float* __restrict__ s0_src,
                                                const float* __restrict__ wv1,
                                                float* __restrict__ s1_src, int n) {
    int w = (int)((blockIdx.x * 256 + threadIdx.x) >> 6);
    int j = threadIdx.x & 63;
    if (w >= n) return;
    int p0 = rowptr[w], p1 = rowptr[w + 1];
    float a0 = hs[(size_t)w * 64 + j];  // self loop
    float a1 = 0.f, a2 = 0.f, a3 = 0.f, a4 = 0.f, a5 = 0.f, a6 = 0.f, a7 = 0.f;
    int p = p0;
    for (; p + 16 <= p1; p += 16) {
        int s0 = csr_src[p],      s1 = csr_src[p + 1],  s2 = csr_src[p + 2],  s3 = csr_src[p + 3];
        int s4 = csr_src[p + 4],  s5 = csr_src[p + 5],  s6 = csr_src[p + 6],  s7 = csr_src[p + 7];
        int s8 = csr_src[p + 8],  s9 = csr_src[p + 9],  sa = csr_src[p + 10], sb = csr_src[p + 11];
        int sc = csr_src[p + 12], sd = csr_src[p + 13], se = csr_src[p + 14], sf = csr_src[p + 15];
        a0 += hs[(size_t)s0 * 64 + j];
        a1 += hs[(size_t)s1 * 64 + j];
        a2 += hs[(size_t)s2 * 64 + j];
        a3 += hs[(size_t)s3 * 64 + j];
        a4 += hs[(size_t)s4 * 64 + j];
        a5 += hs[(size_t)s5 * 64 + j];
        a6 += hs[(size_t)s6 * 64 + j];
        a7 += hs[(size_t)s7 * 64 + j];
        a0 += hs[(size_t)s8 * 64 + j];
        a1 += hs[(size_t)s9 * 64 + j];
        a2 += hs[(size_t)sa * 64 + j];
        a3 += hs[(size_t)sb * 64 + j];
        a4 += hs[(size_t)sc * 64 + j];
        a5 += hs[(size_t)sd * 64 + j];
        a6 += hs[(size_t)se * 64 + j];
        a7 += hs[(size_t)sf * 64 + j];
    }
    int rem = p1 - p;  // 0..15
    if (rem > 0) {
        // predicated full-width tail: clamped indices -> all loads independent;
        // clamped duplicates hit the same line (L1), masked out of the sum.
        int c = p1 - 1;
        int s0 = csr_src[p];
        int s1 = csr_src[(p + 1 < p1) ? p + 1 : c];
        int s2 = csr_src[(p + 2 < p1) ? p + 2 : c];
        int s3 = csr_src[(p + 3 < p1) ? p + 3 : c];
        int s4 = csr_src[(p + 4 < p1) ? p + 4 : c];
        int s5 = csr_src[(p + 5 < p1) ? p + 5 : c];
        int s6 = csr_src[(p + 6 < p1) ? p + 6 : c];
        int s7 = csr_src[(p + 7 < p1) ? p + 7 : c];
        int s8 = csr_src[(p + 8 < p1) ? p + 8 : c];
        int s9 = csr_src[(p + 9 < p1) ? p + 9 : c];
        int sa = csr_src[(p + 10 < p1) ? p + 10 : c];
        int sb = csr_src[(p + 11 < p1) ? p + 11 : c];
        int sc = csr_src[(p + 12 < p1) ? p + 12 : c];
        int sd = csr_src[(p + 13 < p1) ? p + 13 : c];
        int se = csr_src[(p + 14 < p1) ? p + 14 : c];
        a0 += hs[(size_t)s0 * 64 + j];
        a1 += (rem > 1)  ? hs[(size_t)s1 * 64 + j] : 0.f;
        a2 += (rem > 2)  ? hs[(size_t)s2 * 64 + j] : 0.f;
        a3 += (rem > 3)  ? hs[(size_t)s3 * 64 + j] : 0.f;
        a4 += (rem > 4)  ? hs[(size_t)s4 * 64 + j] : 0.f;
        a5 += (rem > 5)  ? hs[(size_t)s5 * 64 + j] : 0.f;
        a6 += (rem > 6)  ? hs[(size_t)s6 * 64 + j] : 0.f;
        a7 += (rem > 7)  ? hs[(size_t)s7 * 64 + j] : 0.f;
        a0 += (rem > 8)  ? hs[(size_t)s8 * 64 + j] : 0.f;
        a1 += (rem > 9)  ? hs[(size_t)s9 * 64 + j] : 0.f;
        a2 += (rem > 10) ? hs[(size_t)sa * 64 + j] : 0.f;
        a3 += (rem > 11) ? hs[(size_t)sb * 64 + j] : 0.f;
        a4 += (rem > 12) ? hs[(size_t)sc * 64 + j] : 0.f;
        a5 += (rem > 13) ? hs[(size_t)sd * 64 + j] : 0.f;
        a6 += (rem > 14) ? hs[(size_t)se * 64 + j] : 0.f;
    }
    float a = ((a0 + a1) + (a2 + a3)) + ((a4 + a5) + (a6 + a7));
    float di = dinv[w];
    float v = fmaxf(a * di + b[j], 0.f);
    h[(size_t)w * 64 + j] = v;
    float t0 = v * wv0[j];
#pragma unroll
    for (int o = 32; o; o >>= 1) t0 += __shfl_xor(t0, o, 64);
    if (j == 0) s0_src[w] = t0 * di;
    if (NDOT == 2) {
        float t1 = v * wv1[j];
#pragma unroll
        for (int o = 32; o; o >>= 1) t1 += __shfl_xor(t1, o, 64);
        if (j == 0) s1_src[w] = t1 * di;
    }
}

// ---------------- triple scalar gather (8-wide batched): sC -> h3,u_src ; sA -> xs1 ; sB -> xs2 ----
__global__ void psg_h3g(const float* __restrict__ sC_src,
                        const float* __restrict__ sA_src,
                        const float* __restrict__ sB_src,
                        const int* __restrict__ rowptr, const int* __restrict__ csr_src,
                        const float* __restrict__ dinv, const float* __restrict__ b3,
                        const float* __restrict__ Ws3,
                        const float* __restrict__ bs1, const float* __restrict__ bs2,
                        float* __restrict__ h3, float* __restrict__ u_src,
                        float* __restrict__ xs1, float* __restrict__ xs2, int n) {
    int i = blockIdx.x * blockDim.x + threadIdx.x;
    if (i >= n) return;
    float aC = sC_src[i], aA = sA_src[i], aB = sB_src[i];
    float C1 = 0.f, C2 = 0.f, C3 = 0.f;
    float A1 = 0.f, A2 = 0.f, A3 = 0.f;
    float B1 = 0.f, B2 = 0.f, B3 = 0.f;
    int p = rowptr[i], p1 = rowptr[i + 1];
    for (; p + 8 <= p1; p += 8) {
        int s0 = csr_src[p],     s1 = csr_src[p + 1], s2 = csr_src[p + 2], s3 = csr_src[p + 3];
        int s4 = csr_src[p + 4], s5 = csr_src[p + 5], s6 = csr_src[p + 6], s7 = csr_src[p + 7];
        aC += sC_src[s0]; C1 += sC_src[s1]; C2 += sC_src[s2]; C3 += sC_src[s3];
        aC += sC_src[s4]; C1 += sC_src[s5]; C2 += sC_src[s6]; C3 += sC_src[s7];
        aA += sA_src[s0]; A1 += sA_src[s1]; A2 += sA_src[s2]; A3 += sA_src[s3];
        aA += sA_src[s4]; A1 += sA_src[s5]; A2 += sA_src[s6]; A3 += sA_src[s7];
        aB += sB_src[s0]; B1 += sB_src[s1]; B2 += sB_src[s2]; B3 += sB_src[s3];
        aB += sB_src[s4]; B1 += sB_src[s5]; B2 += sB_src[s6]; B3 += sB_src[s7];
    }
    int rem = p1 - p;  // 0..7
    if (rem > 0) {
        int c = p1 - 1;
        int s0 = csr_src[p];
        int s1 = csr_src[(p + 1 < p1) ? p + 1 : c];
        int s2 = csr_src[(p + 2 < p1) ? p + 2 : c];
        int s3 = csr_src[(p + 3 < p1) ? p + 3 : c];
        int s4 = csr_src[(p + 4 < p1) ? p + 4 : c];
        int s5 = csr_src[(p + 5 < p1) ? p + 5 : c];
        int s6 = csr_src[(p + 6 < p1) ? p + 6 : c];
        aC += sC_src[s0]; aA += sA_src[s0]; aB += sB_src[s0];
        if (rem > 1) { C1 += sC_src[s1]; A1 += sA_src[s1]; B1 += sB_src[s1]; }
        if (rem > 2) { C2 += sC_src[s2]; A2 += sA_src[s2]; B2 += sB_src[s2]; }
        if (rem > 3) { C3 += sC_src[s3]; A3 += sA_src[s3]; B3 += sB_src[s3]; }
        if (rem > 4) { C1 += sC_src[s4]; A1 += sA_src[s4]; B1 += sB_src[s4]; }
        if (rem > 5) { C2 += sC_src[s5]; A2 += sA_src[s5]; B2 += sB_src[s5]; }
        if (rem > 6) { C3 += sC_src[s6]; A3 += sA_src[s6]; B3 += sB_src[s6]; }
    }
    aC += (C1 + C2) + C3;
    aA += (A1 + A2) + A3;
    aB += (B1 + B2) + B3;
    float di = dinv[i];
    float v = fmaxf(aC * di + b3[0], 0.f);
    h3[i] = v;
    u_src[i] = v * Ws3[0] * di;
    xs1[i] = aA * di + bs1[0];
    xs2[i] = aB * di + bs2[0];
}

// ---------------- second-hop scalar gather (16-wide batched): u_src -> x3 ----------------
__global__ void psg_x3g(const float* __restrict__ u_src,
                        const int* __restrict__ rowptr, const int* __restrict__ csr_src,
                        const float* __restrict__ dinv, const float* __restrict__ bs3,
                        const float* __restrict__ h3, float* __restrict__ x3, int n) {
    int i = blockIdx.x * blockDim.x + threadIdx.x;
    if (i >= n) return;
    float a = u_src[i], u1 = 0.f, u2 = 0.f, u3 = 0.f;
    int p = rowptr[i], p1 = rowptr[i + 1];
    for (; p + 16 <= p1; p += 16) {
#pragma unroll
        for (int k = 0; k < 16; k += 4) {
            int s0 = csr_src[p + k], s1 = csr_src[p + k + 1], s2 = csr_src[p + k + 2], s3 = csr_src[p + k + 3];
            a += u_src[s0]; u1 += u_src[s1]; u2 += u_src[s2]; u3 += u_src[s3];
        }
    }
    int rem = p1 - p;  // 0..15
    if (rem > 0) {
        int c = p1 - 1;
        int s0 = csr_src[p];
        a += u_src[s0];
#pragma unroll
        for (int k = 1; k < 15; ++k) {
            int sk = csr_src[(p + k < p1) ? p + k : c];
            float vk = (rem > k) ? u_src[sk] : 0.f;
            if ((k & 3) == 1) u1 += vk;
            else if ((k & 3) == 2) u2 += vk;
            else if ((k & 3) == 3) u3 += vk;
            else a += vk;
        }
    }
    a += (u1 + u2) + u3;
    x3[i] = (a * dinv[i] + bs3[0]) * h3[i];  // keeps ±0 sign
}

// ---------------- sort-pool + CNN head fused, one block (256 thr) per graph ----------------
// JAX lax.sort uses a float->int total-order transform, so -0.0 < +0.0 STRICTLY.
__device__ __forceinline__ int psg_f2ord(float f) {
    int s = __float_as_int(f);
    return s < 0 ? (s ^ 0x7fffffff) : s;
}

__global__ __launch_bounds__(256) void psg_spcnn(const float* __restrict__ x3,
                                                 const float* __restrict__ xs1,
                                                 const float* __restrict__ xs2,
                                                 const float* __restrict__ h1,
                                                 const float* __restrict__ h2,
                                                 const float* __restrict__ Wc1, const float* __restrict__ bc1,
                                                 const float* __restrict__ Wc2, const float* __restrict__ bc2,
                                                 const float* __restrict__ Wl1, const float* __restrict__ bl1,
                                                 const float* __restrict__ Wl2, const float* __restrict__ bl2,
                                                 float* __restrict__ out) {
    int g = blockIdx.x, t = threadIdx.x;
    __shared__ float pl[KK * 129];
    __shared__ float wc1l[16 * 129];
    __shared__ float wc2l[32 * 16 * 5];
    __shared__ float key[NPG];
    __shared__ int ord[NPG];
    __shared__ int sel[KK];
    __shared__ float sa[KK], sb[KK];
    __shared__ float c1[16 * KK];
    __shared__ float mp[16 * 15];
    __shared__ float c2s[352];
    __shared__ float hdds[128];
    __shared__ float red[2];
    // stage CNN weights early (overlaps the sort phase)
    for (int i = t; i < 16 * 129; i += 256) wc1l[i] = Wc1[i];
    for (int i = t; i < 32 * 16 * 5; i += 256) wc2l[i] = Wc2[i];
    // ---- sort keys (coalesced read; gathers already done upstream)
    if (t < NPG) {
        float v = x3[g * NPG + t];
        key[t] = v;
        ord[t] = psg_f2ord(v);
    }
    __syncthreads();
    if (t < NPG) {
        int v = ord[t];
        int r = 0;
        for (int m = 0; m < NPG; m++) {
            int u = ord[m];
            r += (u > v) || (u == v && m < t);  // stable descending, total order
        }
        if (r < KK) sel[r] = t;
    }
    __syncthreads();
    // stage selected score scalars
    if (t < KK) sa[t] = xs1[g * NPG + sel[t]];
    else if (t >= 32 && t < 32 + KK) sb[t - 32] = xs2[g * NPG + sel[t - 32]];
    __syncthreads();
    // build pooled tile directly in LDS
    for (int idx = t; idx < KK * 129; idx += 256) {
        int r = idx / 129, c = idx - r * 129;
        int node = g * NPG + sel[r];
        float v;
        if (c < 64) v = sa[r] * h1[(size_t)node * 64 + c];
        else if (c < 128) v = sb[r] * h2[(size_t)node * 64 + (c - 64)];
        else v = key[sel[r]];
        pl[idx] = v;
    }
    __syncthreads();
    // conv1d(1->16, k=129, stride=129) + relu
    for (int idx = t; idx < 16 * KK; idx += 256) {
        int c = idx / KK, k = idx % KK;
        float a = bc1[c];
        for (int d = 0; d < 129; d++) a += pl[k * 129 + d] * wc1l[c * 129 + d];
        c1[c * KK + k] = fmaxf(a, 0.f);
    }
    __syncthreads();
    // maxpool1d(2,2)
    for (int idx = t; idx < 16 * 15; idx += 256) {
        int c = idx / 15, k = idx % 15;
        mp[idx] = fmaxf(c1[c * KK + 2 * k], c1[c * KK + 2 * k + 1]);
    }
    __syncthreads();
    // conv1d(16->32, k=5, valid) + relu
    for (int idx = t; idx < 352; idx += 256) {
        int o = idx / 11, k = idx % 11;
        float a = bc2[o];
        for (int i2 = 0; i2 < 16; i2++) {
#pragma unroll
            for (int k2 = 0; k2 < 5; k2++) a += mp[i2 * 15 + k + k2] * wc2l[(o * 16 + i2) * 5 + k2];
        }
        c2s[o * 11 + k] = fmaxf(a, 0.f);
    }
    __syncthreads();
    // linear 352 -> 128 + relu
    if (t < 128) {
        float a = bl1[t];
        const float* wr = Wl1 + (size_t)t * 352;
        for (int f = 0; f < 352; f++) a += c2s[f] * wr[f];
        hdds[t] = fmaxf(a, 0.f);
    }
    __syncthreads();
    // linear 128 -> 1
    if (t < 128) {
        float p = hdds[t] * Wl2[t];
#pragma unroll
        for (int o = 32; o; o >>= 1) p += __shfl_xor(p, o, 64);
        if ((t & 63) == 0) red[t >> 6] = p;
    }
    __syncthreads();
    if (t == 0) out[g] = red[0] + red[1] + bl2[0];
}

extern "C" void kernel_launch(void* const* d_in, const int* in_sizes, int n_in,
                              void* d_out, int out_size, void* d_ws, size_t ws_size,
                              hipStream_t stream) {
    const float* x   = (const float*)d_in[0];
    const int*   ei  = (const int*)d_in[1];
    const float* W1  = (const float*)d_in[2];
    const float* b1  = (const float*)d_in[3];
    const float* W2  = (const float*)d_in[4];
    const float* b2  = (const float*)d_in[5];
    const float* W3  = (const float*)d_in[6];
    const float* b3  = (const float*)d_in[7];
    const float* Ws1 = (const float*)d_in[8];
    const float* bs1 = (const float*)d_in[9];
    const float* Ws2 = (const float*)d_in[10];
    const float* bs2 = (const float*)d_in[11];
    const float* Ws3 = (const float*)d_in[12];
    const float* bs3 = (const float*)d_in[13];
    const float* Wc1 = (const float*)d_in[14];
    const float* bc1 = (const float*)d_in[15];
    const float* Wc2 = (const float*)d_in[16];
    const float* bc2 = (const float*)d_in[17];
    const float* Wl1 = (const float*)d_in[18];
    const float* bl1 = (const float*)d_in[19];
    const float* Wl2 = (const float*)d_in[20];
    const float* bl2 = (const float*)d_in[21];
    float* out = (float*)d_out;

    const int n = in_sizes[0] / FIN;      // 50000
    const int e = in_sizes[1] / 2;        // 600000
    const int* src = ei;
    const int* dst = ei + e;
    const int e4 = e / 4;                 // 150000 (e divisible by 4)
    const int nchunk = (n + SCHUNK - 1) / SCHUNK;  // 49 (<=64)

    // workspace carve-up (~44 MB)
    char* w = (char*)d_ws;
    float* dinv    = (float*)w; w += (size_t)n * 4;
    float* sA_src  = (float*)w; w += (size_t)n * 4;
    float* sB_src  = (float*)w; w += (size_t)n * 4;
    float* sC_src  = (float*)w; w += (size_t)n * 4;
    float* h3      = (float*)w; w += (size_t)n * 4;
    float* u_src   = (float*)w; w += (size_t)n * 4;
    float* xs1     = (float*)w; w += (size_t)n * 4;
    float* xs2     = (float*)w; w += (size_t)n * 4;
    float* x3      = (float*)w; w += (size_t)n * 4;
    int*   deg     = (int*)w;   w += (size_t)n * 4;
    int*   rowptr  = (int*)w;   w += (size_t)(n + 1) * 4;
    int*   rowfill = (int*)w;   w += (size_t)n * 4;
    int*   csums   = (int*)w;   w += 64 * 4;
    int*   csr_src = (int*)w;   w += (size_t)e * 4;
    float* hs      = (float*)w; w += (size_t)n * 64 * 4;  // shared by conv1 & conv2 messages
    float* h1      = (float*)w; w += (size_t)n * 64 * 4;
    float* h2      = (float*)w; w += (size_t)n * 64 * 4;

    const int nb_e4 = (e4 + 255) / 256;
    const int nb_n  = (n + 255) / 256;
    const int nb_g  = (n + 15) / 16;
    const int nb_nw = (n * 64 + 255) / 256;  // one wave per node

    // graph prep: deg -> rowptr (scan, fused dinv) -> CSR build
    hipMemsetAsync(deg, 0, (size_t)n * 4, stream);
    psg_deg<<<nb_e4, 256, 0, stream>>>((const int4*)dst, deg, e4);
    psg_scan1<<<nchunk, SCHUNK, 0, stream>>>(deg, rowptr, csums, dinv, n);
    psg_scan3<<<nchunk, SCHUNK, 0, stream>>>(rowptr, rowfill, csums, n, e);
    psg_build<<<nb_e4, 256, 0, stream>>>((const int4*)src, (const int4*)dst, rowfill, csr_src, e4);

    // ---- conv1: h1 = relu(Ahat (x W1) + b1); dot Ws1 -> sA_src
    psg_gemm<128><<<nb_g, 256, 0, stream>>>(x, W1, dinv, hs, n);
    psg_gfin<1><<<nb_nw, 256, 0, stream>>>(hs, rowptr, csr_src, dinv, b1, h1,
                                           Ws1, sA_src, nullptr, nullptr, n);

    // ---- conv2: h2 = relu(Ahat (h1 W2) + b2); dots Ws2 -> sB, W3 -> sC
    psg_gemm<64><<<nb_g, 256, 0, stream>>>(h1, W2, dinv, hs, n);
    psg_gfin<2><<<nb_nw, 256, 0, stream>>>(hs, rowptr, csr_src, dinv, b2, h2,
                                           Ws2, sB_src, W3, sC_src, n);

    // ---- conv3 (64->1) + score-scalar gathers: h3, u_src, xs1, xs2
    psg_h3g<<<nb_n, 256, 0, stream>>>(sC_src, sA_src, sB_src, rowptr, csr_src, dinv,
                                      b3, Ws3, bs1, bs2, h3, u_src, xs1, xs2, n);
    // ---- score conv second hop: x3 for all nodes
    psg_x3g<<<nb_n, 256, 0, stream>>>(u_src, rowptr, csr_src, dinv, bs3, h3, x3, n);

    // ---- sort-pool + CNN head (no gathers; pooled tile in LDS)
    psg_spcnn<<<GG, 256, 0, stream>>>(x3, xs1, xs2, h1, h2,
                                      Wc1, bc1, Wc2, bc2, Wl1, bl1, Wl2, bl2, out);

    (void)n_in; (void)out_size; (void)ws_size;
}